// Round 1
// baseline (1031.999 us; speedup 1.0000x reference)
//
#include <hip/hip_runtime.h>

typedef __attribute__((ext_vector_type(4))) float    f32x4;
typedef __attribute__((ext_vector_type(8))) short    bf16x8;
typedef __attribute__((ext_vector_type(8))) _Float16 f16x8;
typedef __attribute__((ext_vector_type(4))) _Float16 f16x4;

// ---------- helpers: fp32 <-> bf16 (RNE) ----------
__device__ inline short f2bf(float x) {
    unsigned u = __builtin_bit_cast(unsigned, x);
    unsigned r = (u + 0x7fffu + ((u >> 16) & 1u)) >> 16;
    return (short)r;
}
__device__ inline float bf2f(short s) {
    unsigned u = ((unsigned)(unsigned short)s) << 16;
    return __builtin_bit_cast(float, u);
}

// ---------------------------------------------------------------------------
// GEMM  C[M,N] = A[M,K] @ B[N,K]^T   (NT, both row-major), fp32 in/out,
// computed as bf16x3 split MFMA (hi/lo), 64x64x32 tiles, 4 waves.
// ---------------------------------------------------------------------------
__global__ __launch_bounds__(256) void gemm_nt_split(
    const float* __restrict__ A, const float* __restrict__ Bw,
    float* __restrict__ C, int M, int N, int K)
{
    constexpr int LDW = 40; // padded bf16 row stride (breaks bank aliasing)
    __shared__ short Ah[64 * LDW], Al[64 * LDW], Bh[64 * LDW], Bl[64 * LDW];

    const int tid  = threadIdx.x;
    const int lane = tid & 63;
    const int wv   = tid >> 6;
    const int wm   = wv >> 1, wn = wv & 1;
    const int r    = lane & 15, g = lane >> 4;
    const int m0   = blockIdx.y * 64, n0 = blockIdx.x * 64;
    const int srow = tid >> 2;
    const int scol = (tid & 3) * 8;

    f32x4 acc[2][2];
#pragma unroll
    for (int mf = 0; mf < 2; mf++)
#pragma unroll
        for (int nf = 0; nf < 2; nf++)
            acc[mf][nf] = (f32x4){0.f, 0.f, 0.f, 0.f};

    for (int kk = 0; kk < K; kk += 32) {
        const float* ap = A  + (size_t)(m0 + srow) * K + kk + scol;
        const float* bp = Bw + (size_t)(n0 + srow) * K + kk + scol;
        f32x4 a0 = *(const f32x4*)(ap);
        f32x4 a1 = *(const f32x4*)(ap + 4);
        f32x4 b0 = *(const f32x4*)(bp);
        f32x4 b1 = *(const f32x4*)(bp + 4);

        __syncthreads(); // protect previous iteration's fragment reads

        bf16x8 vah, val, vbh, vbl;
#pragma unroll
        for (int j = 0; j < 4; j++) {
            short h;
            h = f2bf(a0[j]); vah[j]     = h; val[j]     = f2bf(a0[j] - bf2f(h));
            h = f2bf(a1[j]); vah[4 + j] = h; val[4 + j] = f2bf(a1[j] - bf2f(h));
            h = f2bf(b0[j]); vbh[j]     = h; vbl[j]     = f2bf(b0[j] - bf2f(h));
            h = f2bf(b1[j]); vbh[4 + j] = h; vbl[4 + j] = f2bf(b1[j] - bf2f(h));
        }
        *(bf16x8*)&Ah[srow * LDW + scol] = vah;
        *(bf16x8*)&Al[srow * LDW + scol] = val;
        *(bf16x8*)&Bh[srow * LDW + scol] = vbh;
        *(bf16x8*)&Bl[srow * LDW + scol] = vbl;

        __syncthreads();

        bf16x8 fah[2], fal[2], fbh[2], fbl[2];
#pragma unroll
        for (int mf = 0; mf < 2; mf++) {
            int row = (wm * 32 + mf * 16 + r) * LDW + g * 8;
            fah[mf] = *(const bf16x8*)&Ah[row];
            fal[mf] = *(const bf16x8*)&Al[row];
        }
#pragma unroll
        for (int nf = 0; nf < 2; nf++) {
            int row = (wn * 32 + nf * 16 + r) * LDW + g * 8;
            fbh[nf] = *(const bf16x8*)&Bh[row];
            fbl[nf] = *(const bf16x8*)&Bl[row];
        }
#pragma unroll
        for (int mf = 0; mf < 2; mf++)
#pragma unroll
            for (int nf = 0; nf < 2; nf++) {
                acc[mf][nf] = __builtin_amdgcn_mfma_f32_16x16x32_bf16(fal[mf], fbh[nf], acc[mf][nf], 0, 0, 0);
                acc[mf][nf] = __builtin_amdgcn_mfma_f32_16x16x32_bf16(fah[mf], fbl[nf], acc[mf][nf], 0, 0, 0);
                acc[mf][nf] = __builtin_amdgcn_mfma_f32_16x16x32_bf16(fah[mf], fbh[nf], acc[mf][nf], 0, 0, 0);
            }
    }

#pragma unroll
    for (int mf = 0; mf < 2; mf++)
#pragma unroll
        for (int nf = 0; nf < 2; nf++)
#pragma unroll
            for (int e = 0; e < 4; e++) {
                int row = m0 + wm * 32 + mf * 16 + 4 * g + e;
                int col = n0 + wn * 32 + nf * 16 + r;
                C[(size_t)row * N + col] = acc[mf][nf][e];
            }
}

// ---------------------------------------------------------------------------
// RMSNorm + RoPE on Q,K (fp32 -> fp16); V fp32 -> fp16 transposed [h][dh][L].
// grid (L, 3): y=0 Q, y=1 K, y=2 V. 256 threads, 4 fp32 elems/thread.
// ---------------------------------------------------------------------------
__global__ __launch_bounds__(256) void prep_qkv(
    const float* __restrict__ Qf, const float* __restrict__ Kf,
    const float* __restrict__ Vf, const float* __restrict__ rope,
    const float* __restrict__ qg, const float* __restrict__ kg,
    _Float16* __restrict__ Qh, _Float16* __restrict__ Kh,
    _Float16* __restrict__ Vt, int L)
{
    const int l = blockIdx.x, which = blockIdx.y, t = threadIdx.x;
    const int d = t * 4;

    if (which == 2) {
        f32x4 v = *(const f32x4*)(Vf + (size_t)l * 1024 + d);
#pragma unroll
        for (int j = 0; j < 4; j++)
            Vt[(size_t)(d + j) * L + l] = (_Float16)v[j];
        return;
    }

    const float* S = which ? Kf : Qf;
    const float* G = which ? kg : qg;
    f32x4 x = *(const f32x4*)(S + (size_t)l * 1024 + d);
    float ss = x[0] * x[0] + x[1] * x[1] + x[2] * x[2] + x[3] * x[3];
#pragma unroll
    for (int mask = 1; mask < 16; mask <<= 1)
        ss += __shfl_xor(ss, mask);
    const float inv = rsqrtf(ss * (1.0f / 64.0f) + 1e-6f);

    const int dh = d & 63;
    float xn[4];
#pragma unroll
    for (int j = 0; j < 4; j++) xn[j] = x[j] * inv * G[dh + j];
    float pn[4];
#pragma unroll
    for (int j = 0; j < 4; j++) pn[j] = __shfl_xor(xn[j], 8);

    f16x4 outv;
#pragma unroll
    for (int j = 0; j < 4; j++) {
        float ang = rope[(size_t)l * 64 + dh + j];
        float sv, cv;
        __sincosf(ang, &sv, &cv); // fast path; angles O(1), |err| ~1e-6 ok
        float rot = (dh < 32) ? -pn[j] : pn[j];
        outv[j] = (_Float16)(xn[j] * cv + rot * sv);
    }
    _Float16* dst = which ? Kh : Qh;
    *(f16x4*)(dst + (size_t)l * 1024 + d) = outv;
}

// ---------------------------------------------------------------------------
// Flash attention, fp16 MFMA 16x16x32. One block = (64 queries x 1 head),
// 4 waves, each wave 16 queries. K from global [L][16][64], V from global
// transposed [16][64][L]. Online softmax, P via per-wave LDS transpose.
// ---------------------------------------------------------------------------
__global__ __launch_bounds__(256) void flash_attn_f16(
    const _Float16* __restrict__ Qh, const _Float16* __restrict__ Kh,
    const _Float16* __restrict__ Vt, float* __restrict__ AO, int L)
{
    __shared__ _Float16 P[4][16][72];
    const int tid = threadIdx.x, lane = tid & 63, wv = tid >> 6;
    const int r = lane & 15, g = lane >> 4;
    const int h = blockIdx.y;
    const int q0 = blockIdx.x * 64 + wv * 16;

    f16x8 qf[2];
#pragma unroll
    for (int kc = 0; kc < 2; kc++)
        qf[kc] = *(const f16x8*)(Qh + (size_t)(q0 + r) * 1024 + h * 64 + kc * 32 + g * 8);

    float mrun[4], lrun[4];
    f32x4 o[4];
#pragma unroll
    for (int e = 0; e < 4; e++) { mrun[e] = -1e30f; lrun[e] = 0.f; }
#pragma unroll
    for (int nf = 0; nf < 4; nf++) o[nf] = (f32x4){0.f, 0.f, 0.f, 0.f};

    const float CS = 0.18033688011112042f; // (1/8) * log2(e)

    for (int kv = 0; kv < L; kv += 64) {
        f32x4 s[4];
#pragma unroll
        for (int nf = 0; nf < 4; nf++) {
            s[nf] = (f32x4){0.f, 0.f, 0.f, 0.f};
#pragma unroll
            for (int kc = 0; kc < 2; kc++) {
                f16x8 kf = *(const f16x8*)(Kh + (size_t)(kv + nf * 16 + r) * 1024 + h * 64 + kc * 32 + g * 8);
                s[nf] = __builtin_amdgcn_mfma_f32_16x16x32_f16(qf[kc], kf, s[nf], 0, 0, 0);
            }
        }
        // row max (logit2 domain)
        float mx[4];
#pragma unroll
        for (int e = 0; e < 4; e++)
            mx[e] = fmaxf(fmaxf(s[0][e], s[1][e]), fmaxf(s[2][e], s[3][e])) * CS;
#pragma unroll
        for (int mask = 1; mask < 16; mask <<= 1)
#pragma unroll
            for (int e = 0; e < 4; e++)
                mx[e] = fmaxf(mx[e], __shfl_xor(mx[e], mask));

        float mnew[4], alp[4], rs[4];
#pragma unroll
        for (int e = 0; e < 4; e++) {
            mnew[e] = fmaxf(mrun[e], mx[e]);
            alp[e]  = exp2f(mrun[e] - mnew[e]);
            rs[e]   = 0.f;
        }
#pragma unroll
        for (int nf = 0; nf < 4; nf++)
#pragma unroll
            for (int e = 0; e < 4; e++) {
                float p = exp2f(s[nf][e] * CS - mnew[e]);
                s[nf][e] = p;
                rs[e] += p;
            }
#pragma unroll
        for (int mask = 1; mask < 16; mask <<= 1)
#pragma unroll
            for (int e = 0; e < 4; e++)
                rs[e] += __shfl_xor(rs[e], mask);
#pragma unroll
        for (int e = 0; e < 4; e++) {
            lrun[e] = lrun[e] * alp[e] + rs[e];
            mrun[e] = mnew[e];
        }
#pragma unroll
        for (int nf = 0; nf < 4; nf++)
#pragma unroll
            for (int e = 0; e < 4; e++)
                o[nf][e] *= alp[e];

        // P (C-layout) -> LDS at true [q][key], then re-read as A-fragments
#pragma unroll
        for (int nf = 0; nf < 4; nf++)
#pragma unroll
            for (int e = 0; e < 4; e++)
                P[wv][4 * g + e][nf * 16 + r] = (_Float16)s[nf][e];
        asm volatile("s_waitcnt lgkmcnt(0)" ::: "memory");
        f16x8 pa[2];
#pragma unroll
        for (int kc = 0; kc < 2; kc++)
            pa[kc] = *(const f16x8*)&P[wv][r][kc * 32 + g * 8];

#pragma unroll
        for (int nf = 0; nf < 4; nf++)
#pragma unroll
            for (int kc = 0; kc < 2; kc++) {
                f16x8 vf = *(const f16x8*)(Vt + (size_t)(h * 64 + nf * 16 + r) * L + kv + kc * 32 + g * 8);
                o[nf] = __builtin_amdgcn_mfma_f32_16x16x32_f16(pa[kc], vf, o[nf], 0, 0, 0);
            }
    }

#pragma unroll
    for (int nf = 0; nf < 4; nf++)
#pragma unroll
        for (int e = 0; e < 4; e++)
            AO[(size_t)(q0 + 4 * g + e) * 1024 + h * 64 + nf * 16 + r] = o[nf][e] / lrun[e];
}

// ---------------------------------------------------------------------------
extern "C" void kernel_launch(void* const* d_in, const int* in_sizes, int n_in,
                              void* d_out, int out_size, void* d_ws, size_t ws_size,
                              hipStream_t stream)
{
    const float* x    = (const float*)d_in[0];
    const float* rope = (const float*)d_in[1];
    const float* wq   = (const float*)d_in[2];
    const float* wk   = (const float*)d_in[3];
    const float* wv   = (const float*)d_in[4];
    const float* wo   = (const float*)d_in[5];
    const float* qg   = (const float*)d_in[6];
    const float* kg   = (const float*)d_in[7];
    float* out = (float*)d_out;

    const int L = 4800, D = 1024;
    const size_t LD = (size_t)L * D;

    float* Qf = (float*)d_ws;
    float* Kf = Qf + LD;
    float* Vf = Kf + LD;
    _Float16* Qh = (_Float16*)(Vf + LD);
    _Float16* Kh = Qh + LD;
    _Float16* Vt = Kh + LD;
    float* AO = Qf; // alias: Qf dead after prep_qkv

    dim3 gg(D / 64, L / 64);
    gemm_nt_split<<<gg, 256, 0, stream>>>(x, wq, Qf, L, D, D);
    gemm_nt_split<<<gg, 256, 0, stream>>>(x, wk, Kf, L, D, D);
    gemm_nt_split<<<gg, 256, 0, stream>>>(x, wv, Vf, L, D, D);
    prep_qkv<<<dim3(L, 3), 256, 0, stream>>>(Qf, Kf, Vf, rope, qg, kg, Qh, Kh, Vt, L);
    flash_attn_f16<<<dim3(L / 64, 16), 256, 0, stream>>>(Qh, Kh, Vt, AO, L);
    gemm_nt_split<<<gg, 256, 0, stream>>>(AO, wo, out, L, D, D);
}

// Round 2
// 507.397 us; speedup vs baseline: 2.0339x; 2.0339x over previous
//
#include <hip/hip_runtime.h>

typedef __attribute__((ext_vector_type(4)))  float    f32x4;
typedef __attribute__((ext_vector_type(16))) float    f32x16;
typedef __attribute__((ext_vector_type(8)))  short    bf16x8;
typedef __attribute__((ext_vector_type(8)))  _Float16 f16x8;
typedef __attribute__((ext_vector_type(4)))  _Float16 f16x4;

// ---------- helpers: fp32 <-> bf16 (RNE) ----------
__device__ inline short f2bf(float x) {
    unsigned u = __builtin_bit_cast(unsigned, x);
    unsigned r = (u + 0x7fffu + ((u >> 16) & 1u)) >> 16;
    return (short)r;
}
__device__ inline float bf2f(short s) {
    unsigned u = ((unsigned)(unsigned short)s) << 16;
    return __builtin_bit_cast(float, u);
}

// ---------------------------------------------------------------------------
// GEMM  C[M,N] = A[M,K] @ B[N,K]^T   (NT, both row-major), fp32 in/out,
// computed as bf16x3 split MFMA (hi/lo), 64x64x32 tiles, 4 waves.
// ---------------------------------------------------------------------------
__global__ __launch_bounds__(256) void gemm_nt_split(
    const float* __restrict__ A, const float* __restrict__ Bw,
    float* __restrict__ C, int M, int N, int K)
{
    constexpr int LDW = 40;
    __shared__ short Ah[64 * LDW], Al[64 * LDW], Bh[64 * LDW], Bl[64 * LDW];

    const int tid  = threadIdx.x;
    const int lane = tid & 63;
    const int wv   = tid >> 6;
    const int wm   = wv >> 1, wn = wv & 1;
    const int r    = lane & 15, g = lane >> 4;
    const int m0   = blockIdx.y * 64, n0 = blockIdx.x * 64;
    const int srow = tid >> 2;
    const int scol = (tid & 3) * 8;

    f32x4 acc[2][2];
#pragma unroll
    for (int mf = 0; mf < 2; mf++)
#pragma unroll
        for (int nf = 0; nf < 2; nf++)
            acc[mf][nf] = (f32x4){0.f, 0.f, 0.f, 0.f};

    for (int kk = 0; kk < K; kk += 32) {
        const float* ap = A  + (size_t)(m0 + srow) * K + kk + scol;
        const float* bp = Bw + (size_t)(n0 + srow) * K + kk + scol;
        f32x4 a0 = *(const f32x4*)(ap);
        f32x4 a1 = *(const f32x4*)(ap + 4);
        f32x4 b0 = *(const f32x4*)(bp);
        f32x4 b1 = *(const f32x4*)(bp + 4);

        __syncthreads();

        bf16x8 vah, val, vbh, vbl;
#pragma unroll
        for (int j = 0; j < 4; j++) {
            short h;
            h = f2bf(a0[j]); vah[j]     = h; val[j]     = f2bf(a0[j] - bf2f(h));
            h = f2bf(a1[j]); vah[4 + j] = h; val[4 + j] = f2bf(a1[j] - bf2f(h));
            h = f2bf(b0[j]); vbh[j]     = h; vbl[j]     = f2bf(b0[j] - bf2f(h));
            h = f2bf(b1[j]); vbh[4 + j] = h; vbl[4 + j] = f2bf(b1[j] - bf2f(h));
        }
        *(bf16x8*)&Ah[srow * LDW + scol] = vah;
        *(bf16x8*)&Al[srow * LDW + scol] = val;
        *(bf16x8*)&Bh[srow * LDW + scol] = vbh;
        *(bf16x8*)&Bl[srow * LDW + scol] = vbl;

        __syncthreads();

        bf16x8 fah[2], fal[2], fbh[2], fbl[2];
#pragma unroll
        for (int mf = 0; mf < 2; mf++) {
            int row = (wm * 32 + mf * 16 + r) * LDW + g * 8;
            fah[mf] = *(const bf16x8*)&Ah[row];
            fal[mf] = *(const bf16x8*)&Al[row];
        }
#pragma unroll
        for (int nf = 0; nf < 2; nf++) {
            int row = (wn * 32 + nf * 16 + r) * LDW + g * 8;
            fbh[nf] = *(const bf16x8*)&Bh[row];
            fbl[nf] = *(const bf16x8*)&Bl[row];
        }
#pragma unroll
        for (int mf = 0; mf < 2; mf++)
#pragma unroll
            for (int nf = 0; nf < 2; nf++) {
                acc[mf][nf] = __builtin_amdgcn_mfma_f32_16x16x32_bf16(fal[mf], fbh[nf], acc[mf][nf], 0, 0, 0);
                acc[mf][nf] = __builtin_amdgcn_mfma_f32_16x16x32_bf16(fah[mf], fbl[nf], acc[mf][nf], 0, 0, 0);
                acc[mf][nf] = __builtin_amdgcn_mfma_f32_16x16x32_bf16(fah[mf], fbh[nf], acc[mf][nf], 0, 0, 0);
            }
    }

#pragma unroll
    for (int mf = 0; mf < 2; mf++)
#pragma unroll
        for (int nf = 0; nf < 2; nf++)
#pragma unroll
            for (int e = 0; e < 4; e++) {
                int row = m0 + wm * 32 + mf * 16 + 4 * g + e;
                int col = n0 + wn * 32 + nf * 16 + r;
                C[(size_t)row * N + col] = acc[mf][nf][e];
            }
}

// ---------------------------------------------------------------------------
// RMSNorm + RoPE on Q,K (fp32 -> fp16); Q additionally scaled by
// CS = (1/8)*log2(e) so QK^T MFMA output is directly in log2 domain.
// V fp32 -> fp16 transposed [h*64+dh][L]. Q pad rows [4800,4864) zeroed.
// grid (4864, 3): y=0 Q, y=1 K, y=2 V.
// ---------------------------------------------------------------------------
__global__ __launch_bounds__(256) void prep_qkv(
    const float* __restrict__ Qf, const float* __restrict__ Kf,
    const float* __restrict__ Vf, const float* __restrict__ rope,
    const float* __restrict__ qg, const float* __restrict__ kg,
    _Float16* __restrict__ Qh, _Float16* __restrict__ Kh,
    _Float16* __restrict__ Vt, int L)
{
    const int l = blockIdx.x, which = blockIdx.y, t = threadIdx.x;
    const int d = t * 4;

    if (l >= L) {
        if (which == 0) { f16x4 z = {(_Float16)0, (_Float16)0, (_Float16)0, (_Float16)0};
                          *(f16x4*)(Qh + (size_t)l * 1024 + d) = z; }
        return;
    }

    if (which == 2) {
        f32x4 v = *(const f32x4*)(Vf + (size_t)l * 1024 + d);
#pragma unroll
        for (int j = 0; j < 4; j++)
            Vt[(size_t)(d + j) * L + l] = (_Float16)v[j];
        return;
    }

    const float* S = which ? Kf : Qf;
    const float* G = which ? kg : qg;
    const float qscale = which ? 1.0f : 0.18033688011112042f; // (1/8)*log2(e)
    f32x4 x = *(const f32x4*)(S + (size_t)l * 1024 + d);
    float ss = x[0] * x[0] + x[1] * x[1] + x[2] * x[2] + x[3] * x[3];
#pragma unroll
    for (int mask = 1; mask < 16; mask <<= 1)
        ss += __shfl_xor(ss, mask);
    const float inv = rsqrtf(ss * (1.0f / 64.0f) + 1e-6f);

    const int dh = d & 63;
    float xn[4];
#pragma unroll
    for (int j = 0; j < 4; j++) xn[j] = x[j] * inv * G[dh + j];
    float pn[4];
#pragma unroll
    for (int j = 0; j < 4; j++) pn[j] = __shfl_xor(xn[j], 8);

    f16x4 outv;
#pragma unroll
    for (int j = 0; j < 4; j++) {
        float ang = rope[(size_t)l * 64 + dh + j];
        float sv, cv;
        __sincosf(ang, &sv, &cv);
        float rot = (dh < 32) ? -pn[j] : pn[j];
        outv[j] = (_Float16)((xn[j] * cv + rot * sv) * qscale);
    }
    _Float16* dst = which ? Kh : Qh;
    *(f16x4*)(dst + (size_t)l * 1024 + d) = outv;
}

// ---------------------------------------------------------------------------
// Flash attention v2: 32x32x16 f16 MFMA, swapped QK^T, no-max softmax.
// Block = 128 queries x 1 head (4 waves x 32 q). K/V tiles (64 kv) staged in
// LDS (reg-staged, double-buffered, chunk-XOR swizzle for conflict-free
// ds_read_b128), shared across the 4 waves. XCD-swizzled block ids: each
// XCD owns 2 heads -> K/V L2-resident (2.4 MB < 4 MB per-XCD L2).
// p = exp2(s) with no max subtraction: |s| <= 64*(log2e/8) = 11.54 since
// RMSNorm makes |q|=|k|=8 and RoPE is a rotation -> p <= 2980 < f16 max.
// l accumulated per-lane in f32; one shfl at epilogue.
// ---------------------------------------------------------------------------
__global__ __launch_bounds__(256) void flash2(
    const _Float16* __restrict__ Qh, const _Float16* __restrict__ Kh,
    const _Float16* __restrict__ Vt, float* __restrict__ AO, int L)
{
    constexpr int LDP = 72;
    __shared__ _Float16 KT[2][64 * 64];
    __shared__ _Float16 VT[2][64 * 64];
    __shared__ _Float16 PL[4][32 * LDP];
    __shared__ float    LL[4][32];

    const int tid = threadIdx.x, lane = tid & 63, wv = tid >> 6;
    const int r = lane & 31, g2 = lane >> 5;

    // XCD swizzle: hw xcd = blockIdx.x % 8; give each xcd a contiguous
    // 76-block chunk = 2 heads x 38 q-tiles.
    const int idb = (blockIdx.x & 7) * 76 + (blockIdx.x >> 3);
    const int h   = idb / 38;
    const int q0  = (idb % 38) * 128 + wv * 32;

    // Q fragments (B operand): lane r = q row, k(dh) = kc*16 + g2*8 + j
    f16x8 qf[4];
#pragma unroll
    for (int kc = 0; kc < 4; kc++)
        qf[kc] = *(const f16x8*)(Qh + (size_t)(q0 + r) * 1024 + h * 64 + kc * 16 + g2 * 8);

    f32x16 o[2];
#pragma unroll
    for (int nb = 0; nb < 2; nb++)
#pragma unroll
        for (int e = 0; e < 16; e++) o[nb][e] = 0.f;
    float lsum = 0.f;

    // staging geometry: 512 16B-chunks per 8KB tile; thread stages chunks
    // c0 = tid and c1 = 256+tid for both K and V. LDS dest chunk-XOR
    // swizzled: content(row, cb) = global(row, cb ^ (row&7)).
    const int c0 = tid,        c1 = 256 + tid;
    const int r0 = c0 >> 3,    cb0 = c0 & 7;
    const int r1 = c1 >> 3,    cb1 = c1 & 7;
    const int kd0 = r0 * 64 + ((cb0 ^ (r0 & 7)) * 8);
    const int kd1 = r1 * 64 + ((cb1 ^ (r1 & 7)) * 8);

    // prologue: stage tile 0 into buffer 0
    {
        f16x8 a = *(const f16x8*)(Kh + (size_t)r0 * 1024 + h * 64 + cb0 * 8);
        f16x8 b = *(const f16x8*)(Kh + (size_t)r1 * 1024 + h * 64 + cb1 * 8);
        f16x8 c = *(const f16x8*)(Vt + (size_t)(h * 64 + r0) * L + cb0 * 8);
        f16x8 d = *(const f16x8*)(Vt + (size_t)(h * 64 + r1) * L + cb1 * 8);
        *(f16x8*)&KT[0][kd0] = a;  *(f16x8*)&KT[0][kd1] = b;
        *(f16x8*)&VT[0][kd0] = c;  *(f16x8*)&VT[0][kd1] = d;
    }
    __syncthreads();

    const int NT = L / 64; // 75
    for (int t = 0; t < NT; t++) {
        const int cur = t & 1;

        // issue next tile's global loads early (hide HBM/L2 latency under MFMA)
        f16x8 sk0, sk1, sv0, sv1;
        if (t + 1 < NT) {
            const int kv2 = (t + 1) * 64;
            sk0 = *(const f16x8*)(Kh + (size_t)(kv2 + r0) * 1024 + h * 64 + cb0 * 8);
            sk1 = *(const f16x8*)(Kh + (size_t)(kv2 + r1) * 1024 + h * 64 + cb1 * 8);
            sv0 = *(const f16x8*)(Vt + (size_t)(h * 64 + r0) * L + kv2 + cb0 * 8);
            sv1 = *(const f16x8*)(Vt + (size_t)(h * 64 + r1) * L + kv2 + cb1 * 8);
        }

        // ---- swapped QK^T: sc[mk] = mfma(K_frag, Q_frag) -> S^T[key][q]
        f32x16 sc[2];
#pragma unroll
        for (int mk = 0; mk < 2; mk++)
#pragma unroll
            for (int e = 0; e < 16; e++) sc[mk][e] = 0.f;
#pragma unroll
        for (int mk = 0; mk < 2; mk++) {
            const int row = mk * 32 + r;
#pragma unroll
            for (int kc = 0; kc < 4; kc++) {
                f16x8 kf = *(const f16x8*)&KT[cur][row * 64 + (((2 * kc + g2) ^ (row & 7)) * 8)];
                sc[mk] = __builtin_amdgcn_mfma_f32_32x32x16_f16(kf, qf[kc], sc[mk], 0, 0, 0);
            }
        }

        // ---- p = exp2(s), accumulate l, pack 4 consecutive keys -> b64 write
        // C layout: col(q) = lane&31, row(key) = (reg&3) + 8*(reg>>2) + 4*g2 (+32*mk)
#pragma unroll
        for (int mk = 0; mk < 2; mk++)
#pragma unroll
            for (int b = 0; b < 4; b++) {
                float p0 = exp2f(sc[mk][4 * b + 0]);
                float p1 = exp2f(sc[mk][4 * b + 1]);
                float p2 = exp2f(sc[mk][4 * b + 2]);
                float p3 = exp2f(sc[mk][4 * b + 3]);
                lsum += (p0 + p1) + (p2 + p3);
                f16x4 pk = {(_Float16)p0, (_Float16)p1, (_Float16)p2, (_Float16)p3};
                *(f16x4*)&PL[wv][r * LDP + mk * 32 + b * 8 + g2 * 4] = pk;
            }

        // ---- PV: O[q][dh] += mfma(P_frag, V_frag)
        f16x8 pa[4];
#pragma unroll
        for (int kc = 0; kc < 4; kc++)
            pa[kc] = *(const f16x8*)&PL[wv][r * LDP + kc * 16 + g2 * 8];
#pragma unroll
        for (int nb = 0; nb < 2; nb++) {
            const int vrow = nb * 32 + r;
#pragma unroll
            for (int kc = 0; kc < 4; kc++) {
                f16x8 vf = *(const f16x8*)&VT[cur][vrow * 64 + (((2 * kc + g2) ^ (vrow & 7)) * 8)];
                o[nb] = __builtin_amdgcn_mfma_f32_32x32x16_f16(pa[kc], vf, o[nb], 0, 0, 0);
            }
        }

        // write staged next tile into the other buffer, then barrier
        if (t + 1 < NT) {
            const int nxt = cur ^ 1;
            *(f16x8*)&KT[nxt][kd0] = sk0;  *(f16x8*)&KT[nxt][kd1] = sk1;
            *(f16x8*)&VT[nxt][kd0] = sv0;  *(f16x8*)&VT[nxt][kd1] = sv1;
        }
        __syncthreads();
    }

    // epilogue: finish l (pair of lanes per q-col), redistribute via LDS
    lsum += __shfl_xor(lsum, 32);
    LL[wv][r] = lsum;
#pragma unroll
    for (int reg = 0; reg < 16; reg++) {
        const int qrow = (reg & 3) + 8 * (reg >> 2) + 4 * g2;
        const int qg = q0 + qrow;
        if (qg < 4800) {
            const float inv = 1.0f / LL[wv][qrow];
#pragma unroll
            for (int nb = 0; nb < 2; nb++)
                AO[(size_t)qg * 1024 + h * 64 + nb * 32 + r] = o[nb][reg] * inv;
        }
    }
}

// ---------------------------------------------------------------------------
extern "C" void kernel_launch(void* const* d_in, const int* in_sizes, int n_in,
                              void* d_out, int out_size, void* d_ws, size_t ws_size,
                              hipStream_t stream)
{
    const float* x    = (const float*)d_in[0];
    const float* rope = (const float*)d_in[1];
    const float* wq   = (const float*)d_in[2];
    const float* wk   = (const float*)d_in[3];
    const float* wv   = (const float*)d_in[4];
    const float* wo   = (const float*)d_in[5];
    const float* qg   = (const float*)d_in[6];
    const float* kg   = (const float*)d_in[7];
    float* out = (float*)d_out;

    const int L = 4800, D = 1024, Lpad = 4864;
    const size_t LD = (size_t)L * D;

    float* Qf = (float*)d_ws;
    float* Kf = Qf + LD;
    float* Vf = Kf + LD;
    _Float16* Qh = (_Float16*)(Vf + LD);
    _Float16* Kh = Qh + (size_t)Lpad * D;
    _Float16* Vt = Kh + LD;
    float* AO = Qf; // alias: Qf dead after prep_qkv

    dim3 gg(D / 64, L / 64);
    gemm_nt_split<<<gg, 256, 0, stream>>>(x, wq, Qf, L, D, D);
    gemm_nt_split<<<gg, 256, 0, stream>>>(x, wk, Kf, L, D, D);
    gemm_nt_split<<<gg, 256, 0, stream>>>(x, wv, Vf, L, D, D);
    prep_qkv<<<dim3(Lpad, 3), 256, 0, stream>>>(Qf, Kf, Vf, rope, qg, kg, Qh, Kh, Vt, L);
    flash2<<<dim3(608), 256, 0, stream>>>(Qh, Kh, Vt, AO, L);
    gemm_nt_split<<<gg, 256, 0, stream>>>(AO, wo, out, L, D, D);
}

// Round 4
// 416.577 us; speedup vs baseline: 2.4773x; 1.2180x over previous
//
#include <hip/hip_runtime.h>

typedef __attribute__((ext_vector_type(4)))  float    f32x4;
typedef __attribute__((ext_vector_type(16))) float    f32x16;
typedef __attribute__((ext_vector_type(8)))  short    bf16x8;
typedef __attribute__((ext_vector_type(8)))  _Float16 f16x8;
typedef __attribute__((ext_vector_type(4)))  _Float16 f16x4;
typedef __attribute__((ext_vector_type(4)))  unsigned uint4v;

// ---------- helpers ----------
__device__ inline short f2bf(float x) {
    unsigned u = __builtin_bit_cast(unsigned, x);
    unsigned r = (u + 0x7fffu + ((u >> 16) & 1u)) >> 16;
    return (short)r;
}
__device__ inline float bf2f(short s) {
    unsigned u = ((unsigned)(unsigned short)s) << 16;
    return __builtin_bit_cast(float, u);
}
__device__ inline unsigned pkrtz(float a, float b) {
    auto v = __builtin_amdgcn_cvt_pkrtz(a, b);
    return __builtin_bit_cast(unsigned, v);
}
__device__ inline void gld16(void* lds, const void* g) {
    __builtin_amdgcn_global_load_lds(
        (const __attribute__((address_space(1))) void*)g,
        (__attribute__((address_space(3))) void*)lds, 16, 0, 0);
}

// ---------------------------------------------------------------------------
// split fp32 -> bf16 hi/lo pair buffers. n8 = elements/8.
// ---------------------------------------------------------------------------
__global__ __launch_bounds__(256) void split_hl(
    const float* __restrict__ s, short* __restrict__ h, short* __restrict__ l, int n8)
{
    int i = blockIdx.x * 256 + threadIdx.x;
    if (i >= n8) return;
    f32x4 a = ((const f32x4*)s)[2 * i];
    f32x4 b = ((const f32x4*)s)[2 * i + 1];
    bf16x8 hv, lv;
#pragma unroll
    for (int j = 0; j < 4; j++) {
        short t = f2bf(a[j]); hv[j] = t;     lv[j] = f2bf(a[j] - bf2f(t));
        t = f2bf(b[j]);       hv[4 + j] = t; lv[4 + j] = f2bf(b[j] - bf2f(t));
    }
    ((bf16x8*)h)[i] = hv;
    ((bf16x8*)l)[i] = lv;
}

// ---------------------------------------------------------------------------
// GEMM C[M,N] = A @ B^T from PRE-SPLIT bf16 hi/lo pairs (bf16x3 products:
// Ah*Bh + Ah*Bl + Al*Bh). 64x64x32 tiles, 4 waves, fp32 out (stride ldc).
// ---------------------------------------------------------------------------
__global__ __launch_bounds__(256) void gemm3(
    const short* __restrict__ Ah, const short* __restrict__ Al,
    const short* __restrict__ Bh, const short* __restrict__ Bl,
    float* __restrict__ C, int N, int K, int ldc)
{
    constexpr int LDW = 40;
    __shared__ short sAh[64 * LDW], sAl[64 * LDW], sBh[64 * LDW], sBl[64 * LDW];

    const int tid  = threadIdx.x;
    const int lane = tid & 63;
    const int wv   = tid >> 6;
    const int wm   = wv >> 1, wn = wv & 1;
    const int r    = lane & 15, g = lane >> 4;
    const int m0   = blockIdx.y * 64, n0 = blockIdx.x * 64;
    const int srow = tid >> 2;
    const int scol = (tid & 3) * 8;

    const short* pAh = Ah + (size_t)(m0 + srow) * K + scol;
    const short* pAl = Al + (size_t)(m0 + srow) * K + scol;
    const short* pBh = Bh + (size_t)(n0 + srow) * K + scol;
    const short* pBl = Bl + (size_t)(n0 + srow) * K + scol;

    f32x4 acc[2][2];
#pragma unroll
    for (int mf = 0; mf < 2; mf++)
#pragma unroll
        for (int nf = 0; nf < 2; nf++)
            acc[mf][nf] = (f32x4){0.f, 0.f, 0.f, 0.f};

    for (int kk = 0; kk < K; kk += 32) {
        bf16x8 vah = *(const bf16x8*)pAh;
        bf16x8 val = *(const bf16x8*)pAl;
        bf16x8 vbh = *(const bf16x8*)pBh;
        bf16x8 vbl = *(const bf16x8*)pBl;
        pAh += 32; pAl += 32; pBh += 32; pBl += 32;

        __syncthreads();
        *(bf16x8*)&sAh[srow * LDW + scol] = vah;
        *(bf16x8*)&sAl[srow * LDW + scol] = val;
        *(bf16x8*)&sBh[srow * LDW + scol] = vbh;
        *(bf16x8*)&sBl[srow * LDW + scol] = vbl;
        __syncthreads();

        bf16x8 fah[2], fal[2], fbh[2], fbl[2];
#pragma unroll
        for (int mf = 0; mf < 2; mf++) {
            int row = (wm * 32 + mf * 16 + r) * LDW + g * 8;
            fah[mf] = *(const bf16x8*)&sAh[row];
            fal[mf] = *(const bf16x8*)&sAl[row];
        }
#pragma unroll
        for (int nf = 0; nf < 2; nf++) {
            int row = (wn * 32 + nf * 16 + r) * LDW + g * 8;
            fbh[nf] = *(const bf16x8*)&sBh[row];
            fbl[nf] = *(const bf16x8*)&sBl[row];
        }
#pragma unroll
        for (int mf = 0; mf < 2; mf++)
#pragma unroll
            for (int nf = 0; nf < 2; nf++) {
                acc[mf][nf] = __builtin_amdgcn_mfma_f32_16x16x32_bf16(fal[mf], fbh[nf], acc[mf][nf], 0, 0, 0);
                acc[mf][nf] = __builtin_amdgcn_mfma_f32_16x16x32_bf16(fah[mf], fbl[nf], acc[mf][nf], 0, 0, 0);
                acc[mf][nf] = __builtin_amdgcn_mfma_f32_16x16x32_bf16(fah[mf], fbh[nf], acc[mf][nf], 0, 0, 0);
            }
    }

#pragma unroll
    for (int mf = 0; mf < 2; mf++)
#pragma unroll
        for (int nf = 0; nf < 2; nf++)
#pragma unroll
            for (int e = 0; e < 4; e++) {
                int row = m0 + wm * 32 + mf * 16 + 4 * g + e;
                int col = n0 + wn * 32 + nf * 16 + r;
                C[(size_t)row * ldc + col] = acc[mf][nf][e];
            }
}

// ---------------------------------------------------------------------------
// RMSNorm + RoPE on Q,K from fused QKV fp32 (stride 3072) -> fp16.
// Q scaled by (1/8)*log2(e). Q pad rows [4800,4864) zeroed. grid (4864, 2).
// ---------------------------------------------------------------------------
__global__ __launch_bounds__(256) void prep_qk(
    const float* __restrict__ QKVf, const float* __restrict__ rope,
    const float* __restrict__ qg, const float* __restrict__ kg,
    _Float16* __restrict__ Qh, _Float16* __restrict__ Kh, int L)
{
    const int l = blockIdx.x, which = blockIdx.y, t = threadIdx.x;
    const int d = t * 4;

    if (l >= L) {
        if (which == 0) { f16x4 z = {(_Float16)0, (_Float16)0, (_Float16)0, (_Float16)0};
                          *(f16x4*)(Qh + (size_t)l * 1024 + d) = z; }
        return;
    }

    const float* S = QKVf + (size_t)l * 3072 + which * 1024;
    const float* G = which ? kg : qg;
    const float qscale = which ? 1.0f : 0.18033688011112042f;
    f32x4 x = *(const f32x4*)(S + d);
    float ss = x[0] * x[0] + x[1] * x[1] + x[2] * x[2] + x[3] * x[3];
#pragma unroll
    for (int mask = 1; mask < 16; mask <<= 1)
        ss += __shfl_xor(ss, mask);
    const float inv = rsqrtf(ss * (1.0f / 64.0f) + 1e-6f);

    const int dh = d & 63;
    float xn[4];
#pragma unroll
    for (int j = 0; j < 4; j++) xn[j] = x[j] * inv * G[dh + j];
    float pn[4];
#pragma unroll
    for (int j = 0; j < 4; j++) pn[j] = __shfl_xor(xn[j], 8);

    f16x4 outv;
#pragma unroll
    for (int j = 0; j < 4; j++) {
        float ang = rope[(size_t)l * 64 + dh + j];
        float sv, cv;
        __sincosf(ang, &sv, &cv);
        float rot = (dh < 32) ? -pn[j] : pn[j];
        outv[j] = (_Float16)((xn[j] * cv + rot * sv) * qscale);
    }
    _Float16* dst = which ? Kh : Qh;
    *(f16x4*)(dst + (size_t)l * 1024 + d) = outv;
}

// ---------------------------------------------------------------------------
// V: fp32 (fused QKV, col 2048+) -> fp16 transposed [h*64+dh][L], via LDS
// 64x64 tile transpose. grid (75, 16).
// ---------------------------------------------------------------------------
__global__ __launch_bounds__(256) void vtrans(
    const float* __restrict__ QKVf, _Float16* __restrict__ Vt, int L)
{
    __shared__ _Float16 T[64][72];
    const int t = threadIdx.x;
    const int l0 = blockIdx.x * 64, h = blockIdx.y;
    const int lt = t >> 2, dc = (t & 3) * 16;
    const float* src = QKVf + (size_t)(l0 + lt) * 3072 + 2048 + h * 64 + dc;
#pragma unroll
    for (int j = 0; j < 4; j++) {
        f32x4 v = *(const f32x4*)(src + 4 * j);
#pragma unroll
        for (int e = 0; e < 4; e++) T[lt][dc + 4 * j + e] = (_Float16)v[e];
    }
    __syncthreads();
    const int dh = t >> 2, seg = t & 3;
    f16x8 o0, o1;
#pragma unroll
    for (int e = 0; e < 8; e++) {
        o0[e] = T[seg * 16 + e][dh];
        o1[e] = T[seg * 16 + 8 + e][dh];
    }
    _Float16* dst = Vt + (size_t)(h * 64 + dh) * L + l0 + seg * 16;
    *(f16x8*)(dst)     = o0;
    *(f16x8*)(dst + 8) = o1;
}

// ---------------------------------------------------------------------------
// Flash attention v3: 32x32x16 f16 MFMA, swapped QK^T, no-max softmax,
// P kept in registers (cvt_pkrtz + shfl_xor(32) half-exchange, no LDS P).
// K/V tiles double-buffered in LDS via global_load_lds with source-side
// XOR swizzle (linear LDS dest). One barrier per tile; epilogue writes
// AO pre-split to bf16 hi/lo. XCD-swizzled blocks (608 = 8*76).
// ---------------------------------------------------------------------------
__global__ __launch_bounds__(256) void flash3(
    const _Float16* __restrict__ Qh, const _Float16* __restrict__ Kh,
    const _Float16* __restrict__ Vt,
    short* __restrict__ AOh, short* __restrict__ AOl, int L)
{
    __shared__ _Float16 KT[2][4096];
    __shared__ _Float16 VT[2][4096];
    __shared__ float    LL[4][32];

    const int tid = threadIdx.x, lane = tid & 63, wv = tid >> 6;
    const int r = lane & 31, g2 = lane >> 5;

    const int idb = (blockIdx.x & 7) * 76 + (blockIdx.x >> 3);
    const int h   = idb / 38;
    const int q0  = (idb % 38) * 128 + wv * 32;

    // Q fragments (B operand): lane r = q row, k(dh) = kc*16 + g2*8 + j
    f16x8 qf[4];
#pragma unroll
    for (int kc = 0; kc < 4; kc++)
        qf[kc] = *(const f16x8*)(Qh + (size_t)(q0 + r) * 1024 + h * 64 + kc * 16 + g2 * 8);

    // LDS read byte-offsets within a buffer (hoisted; shared by K and V)
    int loff[2][4];
#pragma unroll
    for (int blk = 0; blk < 2; blk++)
#pragma unroll
        for (int kc = 0; kc < 4; kc++)
            loff[blk][kc] = (blk * 32 + r) * 128 + (((2 * kc + g2) ^ (r & 7)) * 16);

    // staging: 512 chunks(16B)/tile, 2 per thread; source pre-swizzled
    const int p0c = tid, p1c = 256 + tid;
    const int sr0 = p0c >> 3, sc0 = (p0c & 7) ^ (sr0 & 7);
    const int sr1 = p1c >> 3, sc1 = (p1c & 7) ^ (sr1 & 7);
    const _Float16* ksrc0 = Kh + (size_t)sr0 * 1024 + h * 64 + sc0 * 8;
    const _Float16* ksrc1 = Kh + (size_t)sr1 * 1024 + h * 64 + sc1 * 8;
    const _Float16* vsrc0 = Vt + (size_t)(h * 64 + sr0) * L + sc0 * 8;
    const _Float16* vsrc1 = Vt + (size_t)(h * 64 + sr1) * L + sc1 * 8;

#define STAGE(buf) do { \
        gld16((char*)&KT[buf][0] + wv * 1024,        ksrc0); \
        gld16((char*)&KT[buf][0] + 4096 + wv * 1024, ksrc1); \
        gld16((char*)&VT[buf][0] + wv * 1024,        vsrc0); \
        gld16((char*)&VT[buf][0] + 4096 + wv * 1024, vsrc1); \
        ksrc0 += 64 * 1024; ksrc1 += 64 * 1024; vsrc0 += 64; vsrc1 += 64; \
    } while (0)

    f32x16 o[2];
#pragma unroll
    for (int nb = 0; nb < 2; nb++)
#pragma unroll
        for (int e = 0; e < 16; e++) o[nb][e] = 0.f;
    float lsum = 0.f;

    STAGE(0);
    __syncthreads();

    // one tile: QK^T -> exp2 -> register P-exchange -> PV
#define TILE(buf, dostage) do { \
        if (dostage) STAGE(buf ^ 1); \
        f32x16 sc_[2]; \
        _Pragma("unroll") for (int e = 0; e < 16; e++) { sc_[0][e] = 0.f; sc_[1][e] = 0.f; } \
        _Pragma("unroll") \
        for (int mk = 0; mk < 2; mk++) \
            _Pragma("unroll") \
            for (int kc = 0; kc < 4; kc++) { \
                f16x8 kf = *(const f16x8*)((const char*)&KT[buf][0] + loff[mk][kc]); \
                sc_[mk] = __builtin_amdgcn_mfma_f32_32x32x16_f16(kf, qf[kc], sc_[mk], 0, 0, 0); \
            } \
        f16x8 pa[4]; \
        _Pragma("unroll") \
        for (int mk = 0; mk < 2; mk++) { \
            float ps[16]; \
            _Pragma("unroll") for (int e = 0; e < 16; e++) ps[e] = exp2f(sc_[mk][e]); \
            _Pragma("unroll") for (int e = 0; e < 16; e++) lsum += ps[e]; \
            _Pragma("unroll") \
            for (int c = 0; c < 2; c++) { \
                unsigned a0 = pkrtz(ps[8 * c + 0], ps[8 * c + 1]); \
                unsigned a1 = pkrtz(ps[8 * c + 2], ps[8 * c + 3]); \
                unsigned b0 = pkrtz(ps[8 * c + 4], ps[8 * c + 5]); \
                unsigned b1 = pkrtz(ps[8 * c + 6], ps[8 * c + 7]); \
                unsigned s0 = g2 ? a0 : b0, s1 = g2 ? a1 : b1; \
                unsigned r0 = (unsigned)__shfl_xor((int)s0, 32); \
                unsigned r1 = (unsigned)__shfl_xor((int)s1, 32); \
                uint4v fr = {g2 ? r0 : a0, g2 ? r1 : a1, g2 ? b0 : r0, g2 ? b1 : r1}; \
                pa[2 * mk + c] = __builtin_bit_cast(f16x8, fr); \
            } \
        } \
        _Pragma("unroll") \
        for (int nb = 0; nb < 2; nb++) \
            _Pragma("unroll") \
            for (int kc = 0; kc < 4; kc++) { \
                f16x8 vf = *(const f16x8*)((const char*)&VT[buf][0] + loff[nb][kc]); \
                o[nb] = __builtin_amdgcn_mfma_f32_32x32x16_f16(pa[kc], vf, o[nb], 0, 0, 0); \
            } \
        __syncthreads(); \
    } while (0)

    for (int t = 0; t + 2 < 75; t += 2) { TILE(0, true); TILE(1, true); }
    TILE(0, false);  // tile 74

#undef TILE
#undef STAGE

    // epilogue: finish l, redistribute via tiny LDS, write AO split hi/lo
    lsum += __shfl_xor(lsum, 32);
    LL[wv][r] = lsum;
#pragma unroll
    for (int reg = 0; reg < 16; reg++) {
        const int qrow = (reg & 3) + 8 * (reg >> 2) + 4 * g2;
        const int qg = q0 + qrow;
        if (qg < 4800) {
            const float inv = 1.0f / LL[wv][qrow];
#pragma unroll
            for (int nb = 0; nb < 2; nb++) {
                float v = o[nb][reg] * inv;
                short hbits = f2bf(v);
                size_t idx = (size_t)qg * 1024 + h * 64 + nb * 32 + r;
                AOh[idx] = hbits;
                AOl[idx] = f2bf(v - bf2f(hbits));
            }
        }
    }
}

// ---------------------------------------------------------------------------
extern "C" void kernel_launch(void* const* d_in, const int* in_sizes, int n_in,
                              void* d_out, int out_size, void* d_ws, size_t ws_size,
                              hipStream_t stream)
{
    const float* x    = (const float*)d_in[0];
    const float* rope = (const float*)d_in[1];
    const float* wq   = (const float*)d_in[2];
    const float* wk   = (const float*)d_in[3];
    const float* wv   = (const float*)d_in[4];
    const float* wo   = (const float*)d_in[5];
    const float* qg   = (const float*)d_in[6];
    const float* kg   = (const float*)d_in[7];
    float* out = (float*)d_out;

    const int L = 4800;
    char* ws = (char*)d_ws;

    // region A (reused): Xh,Xl,Wqkvh,Wqkvl -> later Qh,Kh,Vt
    short* Xh     = (short*)ws;                       // 4800*1024
    short* Xl     = Xh + 4800 * 1024;
    short* Wqkvh  = (short*)(ws + 19660800);          // 3*1024*1024
    short* Wqkvl  = Wqkvh + 3 * 1024 * 1024;
    _Float16* Qh  = (_Float16*)ws;                    // 4864*1024
    _Float16* Kh  = Qh + 4864 * 1024;                 // 4800*1024
    _Float16* Vt  = Kh + 4800 * 1024;                 // 4800*1024
    // region B: Wo split
    short* Woh    = (short*)(ws + 32243712);          // 1024*1024
    short* Wol    = Woh + 1024 * 1024;
    // region C (reused): QKVf fp32 -> later AOh/AOl
    float* QKVf   = (float*)(ws + 36438016);          // 4800*3072
    short* AOh    = (short*)(ws + 36438016);          // 4800*1024
    short* AOl    = AOh + 4800 * 1024;

    split_hl<<<2400, 256, 0, stream>>>(x,  Xh, Xl, 614400);
    split_hl<<<512,  256, 0, stream>>>(wq, Wqkvh,                Wqkvl,                131072);
    split_hl<<<512,  256, 0, stream>>>(wk, Wqkvh + 1024 * 1024,  Wqkvl + 1024 * 1024,  131072);
    split_hl<<<512,  256, 0, stream>>>(wv, Wqkvh + 2048 * 1024,  Wqkvl + 2048 * 1024,  131072);
    split_hl<<<512,  256, 0, stream>>>(wo, Woh, Wol, 131072);

    gemm3<<<dim3(48, 75), 256, 0, stream>>>(Xh, Xl, Wqkvh, Wqkvl, QKVf, 3072, 1024, 3072);
    prep_qk<<<dim3(4864, 2), 256, 0, stream>>>(QKVf, rope, qg, kg, Qh, Kh, L);
    vtrans<<<dim3(75, 16), 256, 0, stream>>>(QKVf, Vt, L);
    flash3<<<608, 256, 0, stream>>>(Qh, Kh, Vt, AOh, AOl, L);
    gemm3<<<dim3(16, 75), 256, 0, stream>>>(AOh, AOl, Woh, Wol, out, 1024, 1024, 1024);
}

// Round 5
// 374.684 us; speedup vs baseline: 2.7543x; 1.1118x over previous
//
#include <hip/hip_runtime.h>

typedef __attribute__((ext_vector_type(4)))  float    f32x4;
typedef __attribute__((ext_vector_type(16))) float    f32x16;
typedef __attribute__((ext_vector_type(8)))  short    bf16x8;
typedef __attribute__((ext_vector_type(4)))  short    short4v;
typedef __attribute__((ext_vector_type(8)))  _Float16 f16x8;
typedef __attribute__((ext_vector_type(4)))  _Float16 f16x4;
typedef __attribute__((ext_vector_type(4)))  unsigned uint4v;

// ---------- helpers ----------
__device__ inline short f2bf(float x) {
    unsigned u = __builtin_bit_cast(unsigned, x);
    unsigned r = (u + 0x7fffu + ((u >> 16) & 1u)) >> 16;
    return (short)r;
}
__device__ inline float bf2f(short s) {
    unsigned u = ((unsigned)(unsigned short)s) << 16;
    return __builtin_bit_cast(float, u);
}
__device__ inline unsigned pkrtz(float a, float b) {
    auto v = __builtin_amdgcn_cvt_pkrtz(a, b);
    return __builtin_bit_cast(unsigned, v);
}
__device__ inline void gld16(void* lds, const void* g) {
    __builtin_amdgcn_global_load_lds(
        (const __attribute__((address_space(1))) void*)g,
        (__attribute__((address_space(3))) void*)lds, 16, 0, 0);
}

// ---------------------------------------------------------------------------
// split fp32 -> bf16 hi/lo pair buffers. n8 = elements/8.
// ---------------------------------------------------------------------------
__global__ __launch_bounds__(256) void split_hl(
    const float* __restrict__ s, short* __restrict__ h, short* __restrict__ l, int n8)
{
    int i = blockIdx.x * 256 + threadIdx.x;
    if (i >= n8) return;
    f32x4 a = ((const f32x4*)s)[2 * i];
    f32x4 b = ((const f32x4*)s)[2 * i + 1];
    bf16x8 hv, lv;
#pragma unroll
    for (int j = 0; j < 4; j++) {
        short t = f2bf(a[j]); hv[j] = t;     lv[j] = f2bf(a[j] - bf2f(t));
        t = f2bf(b[j]);       hv[4 + j] = t; lv[4 + j] = f2bf(b[j] - bf2f(t));
    }
    ((bf16x8*)h)[i] = hv;
    ((bf16x8*)l)[i] = lv;
}

// ---------------------------------------------------------------------------
// GEMM 128x128x32: C = A @ B^T, pre-split bf16 hi/lo, bf16x3 MFMA.
// m97 structure: global_load_lds(16B) staging with source-side XOR swizzle,
// single-buffered 2-barrier K-loop. 4 waves in 2x2, 64x64 out per wave.
// Row guard on C-write (M may not divide 128).
// ---------------------------------------------------------------------------
__global__ __launch_bounds__(256) void gemm128(
    const short* __restrict__ Ah, const short* __restrict__ Al,
    const short* __restrict__ Bh, const short* __restrict__ Bl,
    float* __restrict__ C, int M, int N, int K, int ldc)
{
    __shared__ short sAh[128 * 32], sAl[128 * 32], sBh[128 * 32], sBl[128 * 32];

    const int tid = threadIdx.x, lane = tid & 63, wv = tid >> 6;
    const int wm = wv >> 1, wn = wv & 1;
    const int r = lane & 15, g = lane >> 4;
    const int m0 = blockIdx.y * 128, n0 = blockIdx.x * 128;

    // staging: each panel = 512 16B-chunks; thread stages chunks tid, tid+256.
    // LDS dest linear; source column pre-swizzled: col16 = (c&3) ^ (row&3).
    const int c0 = tid, c1 = tid + 256;
    const int ar0 = c0 >> 2, ac0 = ((c0 & 3) ^ (ar0 & 3)) * 8;
    const int ar1 = c1 >> 2, ac1 = ((c1 & 3) ^ (ar1 & 3)) * 8;
    const size_t offA0 = (size_t)(m0 + ar0) * K + ac0;
    const size_t offA1 = (size_t)(m0 + ar1) * K + ac1;
    const size_t offB0 = (size_t)(n0 + ar0) * K + ac0;
    const size_t offB1 = (size_t)(n0 + ar1) * K + ac1;
    const int d0 = tid * 16, d1 = (tid + 256) * 16;

    f32x4 acc[4][4];
#pragma unroll
    for (int mf = 0; mf < 4; mf++)
#pragma unroll
        for (int nf = 0; nf < 4; nf++)
            acc[mf][nf] = (f32x4){0.f, 0.f, 0.f, 0.f};

    for (int kk = 0; kk < K; kk += 32) {
        __syncthreads();
        gld16((char*)sAh + d0, Ah + offA0 + kk);
        gld16((char*)sAh + d1, Ah + offA1 + kk);
        gld16((char*)sAl + d0, Al + offA0 + kk);
        gld16((char*)sAl + d1, Al + offA1 + kk);
        gld16((char*)sBh + d0, Bh + offB0 + kk);
        gld16((char*)sBh + d1, Bh + offB1 + kk);
        gld16((char*)sBl + d0, Bl + offB0 + kk);
        gld16((char*)sBl + d1, Bl + offB1 + kk);
        __syncthreads();

        bf16x8 fbh[4], fbl[4];
#pragma unroll
        for (int nf = 0; nf < 4; nf++) {
            int row = wn * 64 + nf * 16 + r;
            int byt = row * 64 + ((g ^ (row & 3)) * 16);
            fbh[nf] = *(const bf16x8*)((const char*)sBh + byt);
            fbl[nf] = *(const bf16x8*)((const char*)sBl + byt);
        }
#pragma unroll
        for (int mf = 0; mf < 4; mf++) {
            int row = wm * 64 + mf * 16 + r;
            int byt = row * 64 + ((g ^ (row & 3)) * 16);
            bf16x8 fah = *(const bf16x8*)((const char*)sAh + byt);
            bf16x8 fal = *(const bf16x8*)((const char*)sAl + byt);
#pragma unroll
            for (int nf = 0; nf < 4; nf++) {
                acc[mf][nf] = __builtin_amdgcn_mfma_f32_16x16x32_bf16(fal, fbh[nf], acc[mf][nf], 0, 0, 0);
                acc[mf][nf] = __builtin_amdgcn_mfma_f32_16x16x32_bf16(fah, fbl[nf], acc[mf][nf], 0, 0, 0);
                acc[mf][nf] = __builtin_amdgcn_mfma_f32_16x16x32_bf16(fah, fbh[nf], acc[mf][nf], 0, 0, 0);
            }
        }
    }

#pragma unroll
    for (int mf = 0; mf < 4; mf++)
#pragma unroll
        for (int nf = 0; nf < 4; nf++)
#pragma unroll
            for (int e = 0; e < 4; e++) {
                int row = m0 + wm * 64 + mf * 16 + 4 * g + e;
                int col = n0 + wn * 64 + nf * 16 + r;
                if (row < M) C[(size_t)row * ldc + col] = acc[mf][nf][e];
            }
}

// ---------------------------------------------------------------------------
// GEMM 64x64x32 (R4 version) — used for the out-projection.
// ---------------------------------------------------------------------------
__global__ __launch_bounds__(256) void gemm64(
    const short* __restrict__ Ah, const short* __restrict__ Al,
    const short* __restrict__ Bh, const short* __restrict__ Bl,
    float* __restrict__ C, int N, int K, int ldc)
{
    constexpr int LDW = 40;
    __shared__ short sAh[64 * LDW], sAl[64 * LDW], sBh[64 * LDW], sBl[64 * LDW];

    const int tid  = threadIdx.x;
    const int lane = tid & 63;
    const int wv   = tid >> 6;
    const int wm   = wv >> 1, wn = wv & 1;
    const int r    = lane & 15, g = lane >> 4;
    const int m0   = blockIdx.y * 64, n0 = blockIdx.x * 64;
    const int srow = tid >> 2;
    const int scol = (tid & 3) * 8;

    const short* pAh = Ah + (size_t)(m0 + srow) * K + scol;
    const short* pAl = Al + (size_t)(m0 + srow) * K + scol;
    const short* pBh = Bh + (size_t)(n0 + srow) * K + scol;
    const short* pBl = Bl + (size_t)(n0 + srow) * K + scol;

    f32x4 acc[2][2];
#pragma unroll
    for (int mf = 0; mf < 2; mf++)
#pragma unroll
        for (int nf = 0; nf < 2; nf++)
            acc[mf][nf] = (f32x4){0.f, 0.f, 0.f, 0.f};

    for (int kk = 0; kk < K; kk += 32) {
        bf16x8 vah = *(const bf16x8*)pAh;
        bf16x8 val = *(const bf16x8*)pAl;
        bf16x8 vbh = *(const bf16x8*)pBh;
        bf16x8 vbl = *(const bf16x8*)pBl;
        pAh += 32; pAl += 32; pBh += 32; pBl += 32;

        __syncthreads();
        *(bf16x8*)&sAh[srow * LDW + scol] = vah;
        *(bf16x8*)&sAl[srow * LDW + scol] = val;
        *(bf16x8*)&sBh[srow * LDW + scol] = vbh;
        *(bf16x8*)&sBl[srow * LDW + scol] = vbl;
        __syncthreads();

        bf16x8 fah[2], fal[2], fbh[2], fbl[2];
#pragma unroll
        for (int mf = 0; mf < 2; mf++) {
            int row = (wm * 32 + mf * 16 + r) * LDW + g * 8;
            fah[mf] = *(const bf16x8*)&sAh[row];
            fal[mf] = *(const bf16x8*)&sAl[row];
        }
#pragma unroll
        for (int nf = 0; nf < 2; nf++) {
            int row = (wn * 32 + nf * 16 + r) * LDW + g * 8;
            fbh[nf] = *(const bf16x8*)&sBh[row];
            fbl[nf] = *(const bf16x8*)&sBl[row];
        }
#pragma unroll
        for (int mf = 0; mf < 2; mf++)
#pragma unroll
            for (int nf = 0; nf < 2; nf++) {
                acc[mf][nf] = __builtin_amdgcn_mfma_f32_16x16x32_bf16(fal[mf], fbh[nf], acc[mf][nf], 0, 0, 0);
                acc[mf][nf] = __builtin_amdgcn_mfma_f32_16x16x32_bf16(fah[mf], fbl[nf], acc[mf][nf], 0, 0, 0);
                acc[mf][nf] = __builtin_amdgcn_mfma_f32_16x16x32_bf16(fah[mf], fbh[nf], acc[mf][nf], 0, 0, 0);
            }
    }

#pragma unroll
    for (int mf = 0; mf < 2; mf++)
#pragma unroll
        for (int nf = 0; nf < 2; nf++)
#pragma unroll
            for (int e = 0; e < 4; e++) {
                int row = m0 + wm * 32 + mf * 16 + 4 * g + e;
                int col = n0 + wn * 32 + nf * 16 + r;
                C[(size_t)row * ldc + col] = acc[mf][nf][e];
            }
}

// ---------------------------------------------------------------------------
// RMSNorm + RoPE on Q,K from fused QKV fp32 (stride 3072) -> fp16.
// Q scaled by (1/8)*log2(e). Q pad rows [4800,4864) zeroed. grid (4864, 2).
// ---------------------------------------------------------------------------
__global__ __launch_bounds__(256) void prep_qk(
    const float* __restrict__ QKVf, const float* __restrict__ rope,
    const float* __restrict__ qg, const float* __restrict__ kg,
    _Float16* __restrict__ Qh, _Float16* __restrict__ Kh, int L)
{
    const int l = blockIdx.x, which = blockIdx.y, t = threadIdx.x;
    const int d = t * 4;

    if (l >= L) {
        if (which == 0) { f16x4 z = {(_Float16)0, (_Float16)0, (_Float16)0, (_Float16)0};
                          *(f16x4*)(Qh + (size_t)l * 1024 + d) = z; }
        return;
    }

    const float* S = QKVf + (size_t)l * 3072 + which * 1024;
    const float* G = which ? kg : qg;
    const float qscale = which ? 1.0f : 0.18033688011112042f;
    f32x4 x = *(const f32x4*)(S + d);
    float ss = x[0] * x[0] + x[1] * x[1] + x[2] * x[2] + x[3] * x[3];
#pragma unroll
    for (int mask = 1; mask < 16; mask <<= 1)
        ss += __shfl_xor(ss, mask);
    const float inv = rsqrtf(ss * (1.0f / 64.0f) + 1e-6f);

    const int dh = d & 63;
    float xn[4];
#pragma unroll
    for (int j = 0; j < 4; j++) xn[j] = x[j] * inv * G[dh + j];
    float pn[4];
#pragma unroll
    for (int j = 0; j < 4; j++) pn[j] = __shfl_xor(xn[j], 8);

    f16x4 outv;
#pragma unroll
    for (int j = 0; j < 4; j++) {
        float ang = rope[(size_t)l * 64 + dh + j];
        float sv, cv;
        __sincosf(ang, &sv, &cv);
        float rot = (dh < 32) ? -pn[j] : pn[j];
        outv[j] = (_Float16)((xn[j] * cv + rot * sv) * qscale);
    }
    _Float16* dst = which ? Kh : Qh;
    *(f16x4*)(dst + (size_t)l * 1024 + d) = outv;
}

// ---------------------------------------------------------------------------
// V: fp32 (fused QKV, col 2048+) -> fp16 transposed [h*64+dh][L].
// ---------------------------------------------------------------------------
__global__ __launch_bounds__(256) void vtrans(
    const float* __restrict__ QKVf, _Float16* __restrict__ Vt, int L)
{
    __shared__ _Float16 T[64][72];
    const int t = threadIdx.x;
    const int l0 = blockIdx.x * 64, h = blockIdx.y;
    const int lt = t >> 2, dc = (t & 3) * 16;
    const float* src = QKVf + (size_t)(l0 + lt) * 3072 + 2048 + h * 64 + dc;
#pragma unroll
    for (int j = 0; j < 4; j++) {
        f32x4 v = *(const f32x4*)(src + 4 * j);
#pragma unroll
        for (int e = 0; e < 4; e++) T[lt][dc + 4 * j + e] = (_Float16)v[e];
    }
    __syncthreads();
    const int dh = t >> 2, seg = t & 3;
    f16x8 o0, o1;
#pragma unroll
    for (int e = 0; e < 8; e++) {
        o0[e] = T[seg * 16 + e][dh];
        o1[e] = T[seg * 16 + 8 + e][dh];
    }
    _Float16* dst = Vt + (size_t)(h * 64 + dh) * L + l0 + seg * 16;
    *(f16x8*)(dst)     = o0;
    *(f16x8*)(dst + 8) = o1;
}

// ---------------------------------------------------------------------------
// Flash attention v4: KV-split x2 for occupancy. grid 1216 = 8 XCD x 152.
// Each block: (head h, q-tile qt, kv-half s). Writes unnormalized partial
// O (f32) and partial l to Op/Lp; merge_split combines. Otherwise identical
// to flash3 (32x32x16 f16 MFMA, swapped QK^T, no-max exp2 softmax,
// register-P via cvt_pkrtz + shfl_xor(32), gld_lds-staged K/V dbuf).
// ---------------------------------------------------------------------------
__global__ __launch_bounds__(256) void flash4(
    const _Float16* __restrict__ Qh, const _Float16* __restrict__ Kh,
    const _Float16* __restrict__ Vt,
    float* __restrict__ Op, float* __restrict__ Lp, int L)
{
    __shared__ _Float16 KT[2][4096];
    __shared__ _Float16 VT[2][4096];

    const int tid = threadIdx.x, lane = tid & 63, wv = tid >> 6;
    const int r = lane & 31, g2 = lane >> 5;

    // XCD-chunked id: each XCD owns 2 heads (both kv halves -> L2-resident)
    const int li  = blockIdx.x >> 3;
    const int w   = (blockIdx.x & 7) * 152 + li;
    const int h   = w / 76;
    const int rem = w % 76;
    const int s   = rem / 38;
    const int qt  = rem % 38;
    const int q0  = qt * 128 + wv * 32;
    const int t0  = s * 38;
    const int nt  = s ? 37 : 38;

    f16x8 qf[4];
#pragma unroll
    for (int kc = 0; kc < 4; kc++)
        qf[kc] = *(const f16x8*)(Qh + (size_t)(q0 + r) * 1024 + h * 64 + kc * 16 + g2 * 8);

    int loff[2][4];
#pragma unroll
    for (int blk = 0; blk < 2; blk++)
#pragma unroll
        for (int kc = 0; kc < 4; kc++)
            loff[blk][kc] = (blk * 32 + r) * 128 + (((2 * kc + g2) ^ (r & 7)) * 16);

    const int p0c = tid, p1c = 256 + tid;
    const int sr0 = p0c >> 3, sc0 = (p0c & 7) ^ (sr0 & 7);
    const int sr1 = p1c >> 3, sc1 = (p1c & 7) ^ (sr1 & 7);
    const _Float16* ksrc0 = Kh + (size_t)(t0 * 64 + sr0) * 1024 + h * 64 + sc0 * 8;
    const _Float16* ksrc1 = Kh + (size_t)(t0 * 64 + sr1) * 1024 + h * 64 + sc1 * 8;
    const _Float16* vsrc0 = Vt + (size_t)(h * 64 + sr0) * L + t0 * 64 + sc0 * 8;
    const _Float16* vsrc1 = Vt + (size_t)(h * 64 + sr1) * L + t0 * 64 + sc1 * 8;

#define STAGE(buf) do { \
        gld16((char*)&KT[buf][0] + wv * 1024,        ksrc0); \
        gld16((char*)&KT[buf][0] + 4096 + wv * 1024, ksrc1); \
        gld16((char*)&VT[buf][0] + wv * 1024,        vsrc0); \
        gld16((char*)&VT[buf][0] + 4096 + wv * 1024, vsrc1); \
        ksrc0 += 64 * 1024; ksrc1 += 64 * 1024; vsrc0 += 64; vsrc1 += 64; \
    } while (0)

    f32x16 o[2];
#pragma unroll
    for (int nb = 0; nb < 2; nb++)
#pragma unroll
        for (int e = 0; e < 16; e++) o[nb][e] = 0.f;
    float lsum = 0.f;

    STAGE(0);
    __syncthreads();

#define TILE(buf, dostage) do { \
        if (dostage) STAGE(buf ^ 1); \
        f32x16 sc_[2]; \
        _Pragma("unroll") for (int e = 0; e < 16; e++) { sc_[0][e] = 0.f; sc_[1][e] = 0.f; } \
        _Pragma("unroll") \
        for (int mk = 0; mk < 2; mk++) \
            _Pragma("unroll") \
            for (int kc = 0; kc < 4; kc++) { \
                f16x8 kf = *(const f16x8*)((const char*)&KT[buf][0] + loff[mk][kc]); \
                sc_[mk] = __builtin_amdgcn_mfma_f32_32x32x16_f16(kf, qf[kc], sc_[mk], 0, 0, 0); \
            } \
        f16x8 pa[4]; \
        _Pragma("unroll") \
        for (int mk = 0; mk < 2; mk++) { \
            float ps[16]; \
            _Pragma("unroll") for (int e = 0; e < 16; e++) ps[e] = exp2f(sc_[mk][e]); \
            _Pragma("unroll") for (int e = 0; e < 16; e++) lsum += ps[e]; \
            _Pragma("unroll") \
            for (int c = 0; c < 2; c++) { \
                unsigned a0 = pkrtz(ps[8 * c + 0], ps[8 * c + 1]); \
                unsigned a1 = pkrtz(ps[8 * c + 2], ps[8 * c + 3]); \
                unsigned b0 = pkrtz(ps[8 * c + 4], ps[8 * c + 5]); \
                unsigned b1 = pkrtz(ps[8 * c + 6], ps[8 * c + 7]); \
                unsigned s0 = g2 ? a0 : b0, s1 = g2 ? a1 : b1; \
                unsigned r0 = (unsigned)__shfl_xor((int)s0, 32); \
                unsigned r1 = (unsigned)__shfl_xor((int)s1, 32); \
                uint4v fr = {g2 ? r0 : a0, g2 ? r1 : a1, g2 ? b0 : r0, g2 ? b1 : r1}; \
                pa[2 * mk + c] = __builtin_bit_cast(f16x8, fr); \
            } \
        } \
        _Pragma("unroll") \
        for (int nb = 0; nb < 2; nb++) \
            _Pragma("unroll") \
            for (int kc = 0; kc < 4; kc++) { \
                f16x8 vf = *(const f16x8*)((const char*)&VT[buf][0] + loff[nb][kc]); \
                o[nb] = __builtin_amdgcn_mfma_f32_32x32x16_f16(pa[kc], vf, o[nb], 0, 0, 0); \
            } \
        __syncthreads(); \
    } while (0)

    for (int t = 0; t + 2 < nt; t += 2) { TILE(0, true); TILE(1, true); }
    if (s) { TILE(0, false); }
    else   { TILE(0, true); TILE(1, false); }

#undef TILE
#undef STAGE

    // epilogue: partial l and unnormalized partial O
    lsum += __shfl_xor(lsum, 32);
    if (g2 == 0 && q0 + r < 4800)
        Lp[(size_t)(s * 4800 + q0 + r) * 16 + h] = lsum;
#pragma unroll
    for (int reg = 0; reg < 16; reg++) {
        const int qrow = (reg & 3) + 8 * (reg >> 2) + 4 * g2;
        const int qg = q0 + qrow;
        if (qg < 4800) {
#pragma unroll
            for (int nb = 0; nb < 2; nb++)
                Op[(size_t)(s * 4800 + qg) * 1024 + h * 64 + nb * 32 + r] = o[nb][reg];
        }
    }
}

// ---------------------------------------------------------------------------
// merge the two kv-half partials, normalize, emit bf16 hi/lo split AO.
// grid (4800), 256 threads, 4 elems/thread.
// ---------------------------------------------------------------------------
__global__ __launch_bounds__(256) void merge_split(
    const float* __restrict__ Op, const float* __restrict__ Lp,
    short* __restrict__ AOh, short* __restrict__ AOl)
{
    const int q = blockIdx.x, t = threadIdx.x;
    const int d = t * 4, hh = d >> 6;
    f32x4 a = *(const f32x4*)(Op + (size_t)q * 1024 + d);
    f32x4 b = *(const f32x4*)(Op + (size_t)(4800 + q) * 1024 + d);
    const float inv = 1.0f / (Lp[(size_t)q * 16 + hh] + Lp[(size_t)(4800 + q) * 16 + hh]);
    short4v hv, lv;
#pragma unroll
    for (int j = 0; j < 4; j++) {
        float v = (a[j] + b[j]) * inv;
        short hbits = f2bf(v);
        hv[j] = hbits;
        lv[j] = f2bf(v - bf2f(hbits));
    }
    *(short4v*)(AOh + (size_t)q * 1024 + d) = hv;
    *(short4v*)(AOl + (size_t)q * 1024 + d) = lv;
}

// ---------------------------------------------------------------------------
extern "C" void kernel_launch(void* const* d_in, const int* in_sizes, int n_in,
                              void* d_out, int out_size, void* d_ws, size_t ws_size,
                              hipStream_t stream)
{
    const float* x    = (const float*)d_in[0];
    const float* rope = (const float*)d_in[1];
    const float* wq   = (const float*)d_in[2];
    const float* wk   = (const float*)d_in[3];
    const float* wv   = (const float*)d_in[4];
    const float* wo   = (const float*)d_in[5];
    const float* qg   = (const float*)d_in[6];
    const float* kg   = (const float*)d_in[7];
    float* out = (float*)d_out;

    const int L = 4800;
    char* ws = (char*)d_ws;

    // region A (reused): Xh,Xl,Wqkv -> later Qh,Kh,Vt,Lp
    short* Xh     = (short*)ws;                       // 4800*1024
    short* Xl     = Xh + 4800 * 1024;
    short* Wqkvh  = (short*)(ws + 19660800);          // 3*1024*1024
    short* Wqkvl  = Wqkvh + 3 * 1024 * 1024;          // ends 32243712
    _Float16* Qh  = (_Float16*)ws;                    // 4864*1024  (9961472 B)
    _Float16* Kh  = Qh + 4864 * 1024;                 // 4800*1024  -> 19791872
    _Float16* Vt  = Kh + 4800 * 1024;                 // 4800*1024  -> 29622272
    float* Lp     = (float*)(ws + 29622272);          // 2*4800*16  (614400 B)
    // region B: Wo split
    short* Woh    = (short*)(ws + 32243712);          // 1024*1024
    short* Wol    = Woh + 1024 * 1024;                // ends 36438016
    // region C (reused): QKVf fp32 -> later AOh/AOl + Op
    float* QKVf   = (float*)(ws + 36438016);          // 4800*3072 fp32 -> 95420416
    short* AOh    = (short*)(ws + 36438016);          // 4800*1024
    short* AOl    = AOh + 4800 * 1024;                // ends 56098816
    float* Op     = (float*)(ws + 56098816);          // 2*4800*1024 fp32 -> 95420416

    split_hl<<<2400, 256, 0, stream>>>(x,  Xh, Xl, 614400);
    split_hl<<<512,  256, 0, stream>>>(wq, Wqkvh,                Wqkvl,                131072);
    split_hl<<<512,  256, 0, stream>>>(wk, Wqkvh + 1024 * 1024,  Wqkvl + 1024 * 1024,  131072);
    split_hl<<<512,  256, 0, stream>>>(wv, Wqkvh + 2048 * 1024,  Wqkvl + 2048 * 1024,  131072);
    split_hl<<<512,  256, 0, stream>>>(wo, Woh, Wol, 131072);

    gemm128<<<dim3(24, 38), 256, 0, stream>>>(Xh, Xl, Wqkvh, Wqkvl, QKVf, 4800, 3072, 1024, 3072);
    prep_qk<<<dim3(4864, 2), 256, 0, stream>>>(QKVf, rope, qg, kg, Qh, Kh, L);
    vtrans<<<dim3(75, 16), 256, 0, stream>>>(QKVf, Vt, L);
    flash4<<<1216, 256, 0, stream>>>(Qh, Kh, Vt, Op, Lp, L);
    merge_split<<<4800, 256, 0, stream>>>(Op, Lp, AOh, AOl);
    gemm64<<<dim3(16, 75), 256, 0, stream>>>(AOh, AOl, Woh, Wol, out, 1024, 1024, 1024);
}

// Round 7
// 359.361 us; speedup vs baseline: 2.8718x; 1.0426x over previous
//
#include <hip/hip_runtime.h>

typedef __attribute__((ext_vector_type(4)))  float    f32x4;
typedef __attribute__((ext_vector_type(16))) float    f32x16;
typedef __attribute__((ext_vector_type(8)))  short    bf16x8;
typedef __attribute__((ext_vector_type(4)))  short    short4v;
typedef __attribute__((ext_vector_type(8)))  _Float16 f16x8;
typedef __attribute__((ext_vector_type(4)))  _Float16 f16x4;
typedef __attribute__((ext_vector_type(4)))  unsigned uint4v;
typedef __fp16 h2 __attribute__((ext_vector_type(2)));

// ---------- helpers ----------
__device__ inline short f2bf(float x) {
    unsigned u = __builtin_bit_cast(unsigned, x);
    unsigned r = (u + 0x7fffu + ((u >> 16) & 1u)) >> 16;
    return (short)r;
}
__device__ inline float bf2f(short s) {
    unsigned u = ((unsigned)(unsigned short)s) << 16;
    return __builtin_bit_cast(float, u);
}
__device__ inline unsigned pkrtz(float a, float b) {
    auto v = __builtin_amdgcn_cvt_pkrtz(a, b);
    return __builtin_bit_cast(unsigned, v);
}
__device__ inline void gld16(void* lds, const void* g) {
    __builtin_amdgcn_global_load_lds(
        (const __attribute__((address_space(1))) void*)g,
        (__attribute__((address_space(3))) void*)lds, 16, 0, 0);
}

// half-exchange across the wave's 32-lane halves:
//   a0' = [a0.lo | b0.lo]   (word0 of the A-fragment)
//   b0' = [a0.hi | b0.hi]   (word2 of the A-fragment)
// builtin path lets the compiler insert the required DPP hazard waits
// (raw asm in R6 produced sporadic stale reads -> absmax 4.8e-3).
__device__ inline void half_exchange(unsigned& a0, unsigned& a1,
                                     unsigned& b0, unsigned& b1, int g2) {
#if __has_builtin(__builtin_amdgcn_permlane32_swap)
    {
        auto p = __builtin_amdgcn_permlane32_swap(a0, b0, false, false);
        a0 = p[0]; b0 = p[1];
        auto q = __builtin_amdgcn_permlane32_swap(a1, b1, false, false);
        a1 = q[0]; b1 = q[1];
    }
#else
    unsigned s0 = g2 ? a0 : b0, s1 = g2 ? a1 : b1;
    unsigned r0 = (unsigned)__shfl_xor((int)s0, 32);
    unsigned r1 = (unsigned)__shfl_xor((int)s1, 32);
    unsigned w0 = g2 ? r0 : a0, w1 = g2 ? r1 : a1;
    unsigned w2 = g2 ? b0 : r0, w3 = g2 ? b1 : r1;
    a0 = w0; a1 = w1; b0 = w2; b1 = w3;
#endif
}

// ---------------------------------------------------------------------------
// split fp32 -> bf16 hi/lo pair buffers. n8 = elements/8.
// ---------------------------------------------------------------------------
__global__ __launch_bounds__(256) void split_hl(
    const float* __restrict__ s, short* __restrict__ h, short* __restrict__ l, int n8)
{
    int i = blockIdx.x * 256 + threadIdx.x;
    if (i >= n8) return;
    f32x4 a = ((const f32x4*)s)[2 * i];
    f32x4 b = ((const f32x4*)s)[2 * i + 1];
    bf16x8 hv, lv;
#pragma unroll
    for (int j = 0; j < 4; j++) {
        short t = f2bf(a[j]); hv[j] = t;     lv[j] = f2bf(a[j] - bf2f(t));
        t = f2bf(b[j]);       hv[4 + j] = t; lv[4 + j] = f2bf(b[j] - bf2f(t));
    }
    ((bf16x8*)h)[i] = hv;
    ((bf16x8*)l)[i] = lv;
}

// ---------------------------------------------------------------------------
// GEMM 128x128x32: C = A @ B^T, pre-split bf16 hi/lo, bf16x3 MFMA.
// global_load_lds(16B) staging, source-side XOR swizzle, 2-barrier K-loop.
// ---------------------------------------------------------------------------
__global__ __launch_bounds__(256) void gemm128(
    const short* __restrict__ Ah, const short* __restrict__ Al,
    const short* __restrict__ Bh, const short* __restrict__ Bl,
    float* __restrict__ C, int M, int N, int K, int ldc)
{
    __shared__ short sAh[128 * 32], sAl[128 * 32], sBh[128 * 32], sBl[128 * 32];

    const int tid = threadIdx.x, lane = tid & 63, wv = tid >> 6;
    const int wm = wv >> 1, wn = wv & 1;
    const int r = lane & 15, g = lane >> 4;
    const int m0 = blockIdx.y * 128, n0 = blockIdx.x * 128;

    const int c0 = tid, c1 = tid + 256;
    const int ar0 = c0 >> 2, ac0 = ((c0 & 3) ^ (ar0 & 3)) * 8;
    const int ar1 = c1 >> 2, ac1 = ((c1 & 3) ^ (ar1 & 3)) * 8;
    const size_t offA0 = (size_t)(m0 + ar0) * K + ac0;
    const size_t offA1 = (size_t)(m0 + ar1) * K + ac1;
    const size_t offB0 = (size_t)(n0 + ar0) * K + ac0;
    const size_t offB1 = (size_t)(n0 + ar1) * K + ac1;
    const int d0 = tid * 16, d1 = (tid + 256) * 16;

    f32x4 acc[4][4];
#pragma unroll
    for (int mf = 0; mf < 4; mf++)
#pragma unroll
        for (int nf = 0; nf < 4; nf++)
            acc[mf][nf] = (f32x4){0.f, 0.f, 0.f, 0.f};

    for (int kk = 0; kk < K; kk += 32) {
        __syncthreads();
        gld16((char*)sAh + d0, Ah + offA0 + kk);
        gld16((char*)sAh + d1, Ah + offA1 + kk);
        gld16((char*)sAl + d0, Al + offA0 + kk);
        gld16((char*)sAl + d1, Al + offA1 + kk);
        gld16((char*)sBh + d0, Bh + offB0 + kk);
        gld16((char*)sBh + d1, Bh + offB1 + kk);
        gld16((char*)sBl + d0, Bl + offB0 + kk);
        gld16((char*)sBl + d1, Bl + offB1 + kk);
        __syncthreads();

        bf16x8 fbh[4], fbl[4];
#pragma unroll
        for (int nf = 0; nf < 4; nf++) {
            int row = wn * 64 + nf * 16 + r;
            int byt = row * 64 + ((g ^ (row & 3)) * 16);
            fbh[nf] = *(const bf16x8*)((const char*)sBh + byt);
            fbl[nf] = *(const bf16x8*)((const char*)sBl + byt);
        }
#pragma unroll
        for (int mf = 0; mf < 4; mf++) {
            int row = wm * 64 + mf * 16 + r;
            int byt = row * 64 + ((g ^ (row & 3)) * 16);
            bf16x8 fah = *(const bf16x8*)((const char*)sAh + byt);
            bf16x8 fal = *(const bf16x8*)((const char*)sAl + byt);
#pragma unroll
            for (int nf = 0; nf < 4; nf++) {
                acc[mf][nf] = __builtin_amdgcn_mfma_f32_16x16x32_bf16(fal, fbh[nf], acc[mf][nf], 0, 0, 0);
                acc[mf][nf] = __builtin_amdgcn_mfma_f32_16x16x32_bf16(fah, fbl[nf], acc[mf][nf], 0, 0, 0);
                acc[mf][nf] = __builtin_amdgcn_mfma_f32_16x16x32_bf16(fah, fbh[nf], acc[mf][nf], 0, 0, 0);
            }
        }
    }

#pragma unroll
    for (int mf = 0; mf < 4; mf++)
#pragma unroll
        for (int nf = 0; nf < 4; nf++)
#pragma unroll
            for (int e = 0; e < 4; e++) {
                int row = m0 + wm * 64 + mf * 16 + 4 * g + e;
                int col = n0 + wn * 64 + nf * 16 + r;
                if (row < M) C[(size_t)row * ldc + col] = acc[mf][nf][e];
            }
}

// ---------------------------------------------------------------------------
// RMSNorm + RoPE on Q,K from fused QKV fp32 (stride 3072) -> fp16.
// ---------------------------------------------------------------------------
__global__ __launch_bounds__(256) void prep_qk(
    const float* __restrict__ QKVf, const float* __restrict__ rope,
    const float* __restrict__ qg, const float* __restrict__ kg,
    _Float16* __restrict__ Qh, _Float16* __restrict__ Kh, int L)
{
    const int l = blockIdx.x, which = blockIdx.y, t = threadIdx.x;
    const int d = t * 4;

    if (l >= L) {
        if (which == 0) { f16x4 z = {(_Float16)0, (_Float16)0, (_Float16)0, (_Float16)0};
                          *(f16x4*)(Qh + (size_t)l * 1024 + d) = z; }
        return;
    }

    const float* S = QKVf + (size_t)l * 3072 + which * 1024;
    const float* G = which ? kg : qg;
    const float qscale = which ? 1.0f : 0.18033688011112042f;
    f32x4 x = *(const f32x4*)(S + d);
    float ss = x[0] * x[0] + x[1] * x[1] + x[2] * x[2] + x[3] * x[3];
#pragma unroll
    for (int mask = 1; mask < 16; mask <<= 1)
        ss += __shfl_xor(ss, mask);
    const float inv = rsqrtf(ss * (1.0f / 64.0f) + 1e-6f);

    const int dh = d & 63;
    float xn[4];
#pragma unroll
    for (int j = 0; j < 4; j++) xn[j] = x[j] * inv * G[dh + j];
    float pn[4];
#pragma unroll
    for (int j = 0; j < 4; j++) pn[j] = __shfl_xor(xn[j], 8);

    f16x4 outv;
#pragma unroll
    for (int j = 0; j < 4; j++) {
        float ang = rope[(size_t)l * 64 + dh + j];
        float sv, cv;
        __sincosf(ang, &sv, &cv);
        float rot = (dh < 32) ? -pn[j] : pn[j];
        outv[j] = (_Float16)((xn[j] * cv + rot * sv) * qscale);
    }
    _Float16* dst = which ? Kh : Qh;
    *(f16x4*)(dst + (size_t)l * 1024 + d) = outv;
}

// ---------------------------------------------------------------------------
// V: fp32 (fused QKV, col 2048+) -> fp16 transposed [h*64+dh][L].
// ---------------------------------------------------------------------------
__global__ __launch_bounds__(256) void vtrans(
    const float* __restrict__ QKVf, _Float16* __restrict__ Vt, int L)
{
    __shared__ _Float16 T[64][72];
    const int t = threadIdx.x;
    const int l0 = blockIdx.x * 64, h = blockIdx.y;
    const int lt = t >> 2, dc = (t & 3) * 16;
    const float* src = QKVf + (size_t)(l0 + lt) * 3072 + 2048 + h * 64 + dc;
#pragma unroll
    for (int j = 0; j < 4; j++) {
        f32x4 v = *(const f32x4*)(src + 4 * j);
#pragma unroll
        for (int e = 0; e < 4; e++) T[lt][dc + 4 * j + e] = (_Float16)v[e];
    }
    __syncthreads();
    const int dh = t >> 2, seg = t & 3;
    f16x8 o0, o1;
#pragma unroll
    for (int e = 0; e < 8; e++) {
        o0[e] = T[seg * 16 + e][dh];
        o1[e] = T[seg * 16 + 8 + e][dh];
    }
    _Float16* dst = Vt + (size_t)(h * 64 + dh) * L + l0 + seg * 16;
    *(f16x8*)(dst)     = o0;
    *(f16x8*)(dst + 8) = o1;
}

// ---------------------------------------------------------------------------
// Flash attention v6: flash5 with the half-exchange done via the
// __builtin_amdgcn_permlane32_swap builtin (hazard-safe) instead of raw asm.
// z16 hoisted C-in zero; lsum via v_dot2_f32_f16 on post-swap P words.
// ---------------------------------------------------------------------------
__global__ __launch_bounds__(256) void flash6(
    const _Float16* __restrict__ Qh, const _Float16* __restrict__ Kh,
    const _Float16* __restrict__ Vt,
    float* __restrict__ Op, float* __restrict__ Lp, int L)
{
    __shared__ _Float16 KT[2][4096];
    __shared__ _Float16 VT[2][4096];

    const int tid = threadIdx.x, lane = tid & 63, wv = tid >> 6;
    const int r = lane & 31, g2 = lane >> 5;

    const int li  = blockIdx.x >> 3;
    const int w   = (blockIdx.x & 7) * 152 + li;
    const int h   = w / 76;
    const int rem = w % 76;
    const int s   = rem / 38;
    const int qt  = rem % 38;
    const int q0  = qt * 128 + wv * 32;
    const int t0  = s * 38;
    const int nt  = s ? 37 : 38;

    f16x8 qf[4];
#pragma unroll
    for (int kc = 0; kc < 4; kc++)
        qf[kc] = *(const f16x8*)(Qh + (size_t)(q0 + r) * 1024 + h * 64 + kc * 16 + g2 * 8);

    int loff[2][4];
#pragma unroll
    for (int blk = 0; blk < 2; blk++)
#pragma unroll
        for (int kc = 0; kc < 4; kc++)
            loff[blk][kc] = (blk * 32 + r) * 128 + (((2 * kc + g2) ^ (r & 7)) * 16);

    const int p0c = tid, p1c = 256 + tid;
    const int sr0 = p0c >> 3, sc0 = (p0c & 7) ^ (sr0 & 7);
    const int sr1 = p1c >> 3, sc1 = (p1c & 7) ^ (sr1 & 7);
    const _Float16* ksrc0 = Kh + (size_t)(t0 * 64 + sr0) * 1024 + h * 64 + sc0 * 8;
    const _Float16* ksrc1 = Kh + (size_t)(t0 * 64 + sr1) * 1024 + h * 64 + sc1 * 8;
    const _Float16* vsrc0 = Vt + (size_t)(h * 64 + sr0) * L + t0 * 64 + sc0 * 8;
    const _Float16* vsrc1 = Vt + (size_t)(h * 64 + sr1) * L + t0 * 64 + sc1 * 8;

#define STAGE(buf) do { \
        gld16((char*)&KT[buf][0] + wv * 1024,        ksrc0); \
        gld16((char*)&KT[buf][0] + 4096 + wv * 1024, ksrc1); \
        gld16((char*)&VT[buf][0] + wv * 1024,        vsrc0); \
        gld16((char*)&VT[buf][0] + 4096 + wv * 1024, vsrc1); \
        ksrc0 += 64 * 1024; ksrc1 += 64 * 1024; vsrc0 += 64; vsrc1 += 64; \
    } while (0)

    f32x16 o[2];
#pragma unroll
    for (int nb = 0; nb < 2; nb++)
#pragma unroll
        for (int e = 0; e < 16; e++) o[nb][e] = 0.f;
    float lsum = 0.f;

    f32x16 z16;
#pragma unroll
    for (int e = 0; e < 16; e++) z16[e] = 0.f;
    const h2 ones2 = {(__fp16)1.0f, (__fp16)1.0f};

    STAGE(0);
    __syncthreads();

#define TILE(buf, dostage) do { \
        if (dostage) STAGE(buf ^ 1); \
        f32x16 sc_[2]; \
        _Pragma("unroll") \
        for (int mk = 0; mk < 2; mk++) { \
            f16x8 kf0 = *(const f16x8*)((const char*)&KT[buf][0] + loff[mk][0]); \
            sc_[mk] = __builtin_amdgcn_mfma_f32_32x32x16_f16(kf0, qf[0], z16, 0, 0, 0); \
            _Pragma("unroll") \
            for (int kc = 1; kc < 4; kc++) { \
                f16x8 kf = *(const f16x8*)((const char*)&KT[buf][0] + loff[mk][kc]); \
                sc_[mk] = __builtin_amdgcn_mfma_f32_32x32x16_f16(kf, qf[kc], sc_[mk], 0, 0, 0); \
            } \
        } \
        f16x8 pa[4]; \
        _Pragma("unroll") \
        for (int mk = 0; mk < 2; mk++) { \
            float ps[16]; \
            _Pragma("unroll") for (int e = 0; e < 16; e++) ps[e] = exp2f(sc_[mk][e]); \
            _Pragma("unroll") \
            for (int c = 0; c < 2; c++) { \
                unsigned a0 = pkrtz(ps[8 * c + 0], ps[8 * c + 1]); \
                unsigned a1 = pkrtz(ps[8 * c + 2], ps[8 * c + 3]); \
                unsigned b0 = pkrtz(ps[8 * c + 4], ps[8 * c + 5]); \
                unsigned b1 = pkrtz(ps[8 * c + 6], ps[8 * c + 7]); \
                half_exchange(a0, a1, b0, b1, g2); \
                lsum = __builtin_amdgcn_fdot2(__builtin_bit_cast(h2, a0), ones2, lsum, false); \
                lsum = __builtin_amdgcn_fdot2(__builtin_bit_cast(h2, a1), ones2, lsum, false); \
                lsum = __builtin_amdgcn_fdot2(__builtin_bit_cast(h2, b0), ones2, lsum, false); \
                lsum = __builtin_amdgcn_fdot2(__builtin_bit_cast(h2, b1), ones2, lsum, false); \
                uint4v fr = {a0, a1, b0, b1}; \
                pa[2 * mk + c] = __builtin_bit_cast(f16x8, fr); \
            } \
        } \
        _Pragma("unroll") \
        for (int nb = 0; nb < 2; nb++) \
            _Pragma("unroll") \
            for (int kc = 0; kc < 4; kc++) { \
                f16x8 vf = *(const f16x8*)((const char*)&VT[buf][0] + loff[nb][kc]); \
                o[nb] = __builtin_amdgcn_mfma_f32_32x32x16_f16(pa[kc], vf, o[nb], 0, 0, 0); \
            } \
        __syncthreads(); \
    } while (0)

    for (int t = 0; t + 2 < nt; t += 2) { TILE(0, true); TILE(1, true); }
    if (s) { TILE(0, false); }
    else   { TILE(0, true); TILE(1, false); }

#undef TILE
#undef STAGE

    lsum += __shfl_xor(lsum, 32);
    if (g2 == 0 && q0 + r < 4800)
        Lp[(size_t)(s * 4800 + q0 + r) * 16 + h] = lsum;
#pragma unroll
    for (int reg = 0; reg < 16; reg++) {
        const int qrow = (reg & 3) + 8 * (reg >> 2) + 4 * g2;
        const int qg = q0 + qrow;
        if (qg < 4800) {
#pragma unroll
            for (int nb = 0; nb < 2; nb++)
                Op[(size_t)(s * 4800 + qg) * 1024 + h * 64 + nb * 32 + r] = o[nb][reg];
        }
    }
}

// ---------------------------------------------------------------------------
// merge the two kv-half partials, normalize, emit bf16 hi/lo split AO.
// ---------------------------------------------------------------------------
__global__ __launch_bounds__(256) void merge_split(
    const float* __restrict__ Op, const float* __restrict__ Lp,
    short* __restrict__ AOh, short* __restrict__ AOl)
{
    const int q = blockIdx.x, t = threadIdx.x;
    const int d = t * 4, hh = d >> 6;
    f32x4 a = *(const f32x4*)(Op + (size_t)q * 1024 + d);
    f32x4 b = *(const f32x4*)(Op + (size_t)(4800 + q) * 1024 + d);
    const float inv = 1.0f / (Lp[(size_t)q * 16 + hh] + Lp[(size_t)(4800 + q) * 16 + hh]);
    short4v hv, lv;
#pragma unroll
    for (int j = 0; j < 4; j++) {
        float v = (a[j] + b[j]) * inv;
        short hbits = f2bf(v);
        hv[j] = hbits;
        lv[j] = f2bf(v - bf2f(hbits));
    }
    *(short4v*)(AOh + (size_t)q * 1024 + d) = hv;
    *(short4v*)(AOl + (size_t)q * 1024 + d) = lv;
}

// ---------------------------------------------------------------------------
extern "C" void kernel_launch(void* const* d_in, const int* in_sizes, int n_in,
                              void* d_out, int out_size, void* d_ws, size_t ws_size,
                              hipStream_t stream)
{
    const float* x    = (const float*)d_in[0];
    const float* rope = (const float*)d_in[1];
    const float* wq   = (const float*)d_in[2];
    const float* wk   = (const float*)d_in[3];
    const float* wv   = (const float*)d_in[4];
    const float* wo   = (const float*)d_in[5];
    const float* qg   = (const float*)d_in[6];
    const float* kg   = (const float*)d_in[7];
    float* out = (float*)d_out;

    const int L = 4800;
    char* ws = (char*)d_ws;

    short* Xh     = (short*)ws;
    short* Xl     = Xh + 4800 * 1024;
    short* Wqkvh  = (short*)(ws + 19660800);
    short* Wqkvl  = Wqkvh + 3 * 1024 * 1024;
    _Float16* Qh  = (_Float16*)ws;
    _Float16* Kh  = Qh + 4864 * 1024;
    _Float16* Vt  = Kh + 4800 * 1024;
    float* Lp     = (float*)(ws + 29622272);
    short* Woh    = (short*)(ws + 32243712);
    short* Wol    = Woh + 1024 * 1024;
    float* QKVf   = (float*)(ws + 36438016);
    short* AOh    = (short*)(ws + 36438016);
    short* AOl    = AOh + 4800 * 1024;
    float* Op     = (float*)(ws + 56098816);

    split_hl<<<2400, 256, 0, stream>>>(x,  Xh, Xl, 614400);
    split_hl<<<512,  256, 0, stream>>>(wq, Wqkvh,                Wqkvl,                131072);
    split_hl<<<512,  256, 0, stream>>>(wk, Wqkvh + 1024 * 1024,  Wqkvl + 1024 * 1024,  131072);
    split_hl<<<512,  256, 0, stream>>>(wv, Wqkvh + 2048 * 1024,  Wqkvl + 2048 * 1024,  131072);
    split_hl<<<512,  256, 0, stream>>>(wo, Woh, Wol, 131072);

    gemm128<<<dim3(24, 38), 256, 0, stream>>>(Xh, Xl, Wqkvh, Wqkvl, QKVf, 4800, 3072, 1024, 3072);
    prep_qk<<<dim3(4864, 2), 256, 0, stream>>>(QKVf, rope, qg, kg, Qh, Kh, L);
    vtrans<<<dim3(75, 16), 256, 0, stream>>>(QKVf, Vt, L);
    flash6<<<1216, 256, 0, stream>>>(Qh, Kh, Vt, Op, Lp, L);
    merge_split<<<4800, 256, 0, stream>>>(Op, Lp, AOh, AOl);
    gemm128<<<dim3(8, 38), 256, 0, stream>>>(AOh, AOl, Woh, Wol, out, 4800, 1024, 1024, 1024);
}

// Round 8
// 317.513 us; speedup vs baseline: 3.2503x; 1.1318x over previous
//
#include <hip/hip_runtime.h>

typedef __attribute__((ext_vector_type(4)))  float    f32x4;
typedef __attribute__((ext_vector_type(16))) float    f32x16;
typedef __attribute__((ext_vector_type(8)))  short    bf16x8;
typedef __attribute__((ext_vector_type(4)))  short    short4v;
typedef __attribute__((ext_vector_type(8)))  _Float16 f16x8;
typedef __attribute__((ext_vector_type(4)))  _Float16 f16x4;
typedef __attribute__((ext_vector_type(4)))  unsigned uint4v;
typedef __fp16 h2 __attribute__((ext_vector_type(2)));

// ---------- helpers ----------
__device__ inline short f2bf(float x) {
    unsigned u = __builtin_bit_cast(unsigned, x);
    unsigned r = (u + 0x7fffu + ((u >> 16) & 1u)) >> 16;
    return (short)r;
}
__device__ inline float bf2f(short s) {
    unsigned u = ((unsigned)(unsigned short)s) << 16;
    return __builtin_bit_cast(float, u);
}
__device__ inline unsigned pkrtz(float a, float b) {
    auto v = __builtin_amdgcn_cvt_pkrtz(a, b);
    return __builtin_bit_cast(unsigned, v);
}
// raw v_exp_f32: safe here (|arg| <= 11.6 -> fully normal range, ~1 ULP)
__device__ inline float fexp2(float x) {
#if __has_builtin(__builtin_amdgcn_exp2f)
    return __builtin_amdgcn_exp2f(x);
#else
    return exp2f(x);
#endif
}
__device__ inline void gld16(void* lds, const void* g) {
    __builtin_amdgcn_global_load_lds(
        (const __attribute__((address_space(1))) void*)g,
        (__attribute__((address_space(3))) void*)lds, 16, 0, 0);
}

// half-exchange across the wave's 32-lane halves (hazard-safe builtin path;
// raw asm version produced sporadic stale reads in R6).
__device__ inline void half_exchange(unsigned& a0, unsigned& a1,
                                     unsigned& b0, unsigned& b1, int g2) {
#if __has_builtin(__builtin_amdgcn_permlane32_swap)
    {
        auto p = __builtin_amdgcn_permlane32_swap(a0, b0, false, false);
        a0 = p[0]; b0 = p[1];
        auto q = __builtin_amdgcn_permlane32_swap(a1, b1, false, false);
        a1 = q[0]; b1 = q[1];
    }
#else
    unsigned s0 = g2 ? a0 : b0, s1 = g2 ? a1 : b1;
    unsigned r0 = (unsigned)__shfl_xor((int)s0, 32);
    unsigned r1 = (unsigned)__shfl_xor((int)s1, 32);
    unsigned w0 = g2 ? r0 : a0, w1 = g2 ? r1 : a1;
    unsigned w2 = g2 ? b0 : r0, w3 = g2 ? b1 : r1;
    a0 = w0; a1 = w1; b0 = w2; b1 = w3;
#endif
}

// ---------------------------------------------------------------------------
// fused split fp32 -> bf16 hi/lo for x, wq, wk, wv, wo (one launch).
// segments (blocks): [0,2400) x | [2400,2912) wq | [2912,3424) wk
//                    | [3424,3936) wv | [3936,4448) wo
// ---------------------------------------------------------------------------
__global__ __launch_bounds__(256) void split_all(
    const float* __restrict__ x,  const float* __restrict__ wq,
    const float* __restrict__ wk, const float* __restrict__ wv,
    const float* __restrict__ wo,
    short* __restrict__ Xh, short* __restrict__ Xl,
    short* __restrict__ Wqkvh, short* __restrict__ Wqkvl,
    short* __restrict__ Woh, short* __restrict__ Wol)
{
    const int b = blockIdx.x;
    const float* s; short* h; short* l; int i;
    if (b < 2400)      { s = x;  h = Xh;    l = Xl;    i = b * 256 + threadIdx.x; }
    else if (b < 2912) { s = wq; h = Wqkvh; l = Wqkvl; i = (b - 2400) * 256 + threadIdx.x; }
    else if (b < 3424) { s = wk; h = Wqkvh + 1024 * 1024; l = Wqkvl + 1024 * 1024; i = (b - 2912) * 256 + threadIdx.x; }
    else if (b < 3936) { s = wv; h = Wqkvh + 2048 * 1024; l = Wqkvl + 2048 * 1024; i = (b - 3424) * 256 + threadIdx.x; }
    else               { s = wo; h = Woh;   l = Wol;   i = (b - 3936) * 256 + threadIdx.x; }

    f32x4 a = ((const f32x4*)s)[2 * i];
    f32x4 c = ((const f32x4*)s)[2 * i + 1];
    bf16x8 hv, lv;
#pragma unroll
    for (int j = 0; j < 4; j++) {
        short t = f2bf(a[j]); hv[j] = t;     lv[j] = f2bf(a[j] - bf2f(t));
        t = f2bf(c[j]);       hv[4 + j] = t; lv[4 + j] = f2bf(c[j] - bf2f(t));
    }
    ((bf16x8*)h)[i] = hv;
    ((bf16x8*)l)[i] = lv;
}

// ---------------------------------------------------------------------------
// GEMM 128x128x32: C = A @ B^T, pre-split bf16 hi/lo, bf16x3 MFMA.
// global_load_lds(16B) staging, source-side XOR swizzle, 2-barrier K-loop.
// ---------------------------------------------------------------------------
__global__ __launch_bounds__(256) void gemm128(
    const short* __restrict__ Ah, const short* __restrict__ Al,
    const short* __restrict__ Bh, const short* __restrict__ Bl,
    float* __restrict__ C, int M, int N, int K, int ldc)
{
    __shared__ short sAh[128 * 32], sAl[128 * 32], sBh[128 * 32], sBl[128 * 32];

    const int tid = threadIdx.x, lane = tid & 63, wv = tid >> 6;
    const int wm = wv >> 1, wn = wv & 1;
    const int r = lane & 15, g = lane >> 4;
    const int m0 = blockIdx.y * 128, n0 = blockIdx.x * 128;

    const int c0 = tid, c1 = tid + 256;
    const int ar0 = c0 >> 2, ac0 = ((c0 & 3) ^ (ar0 & 3)) * 8;
    const int ar1 = c1 >> 2, ac1 = ((c1 & 3) ^ (ar1 & 3)) * 8;
    const size_t offA0 = (size_t)(m0 + ar0) * K + ac0;
    const size_t offA1 = (size_t)(m0 + ar1) * K + ac1;
    const size_t offB0 = (size_t)(n0 + ar0) * K + ac0;
    const size_t offB1 = (size_t)(n0 + ar1) * K + ac1;
    const int d0 = tid * 16, d1 = (tid + 256) * 16;

    f32x4 acc[4][4];
#pragma unroll
    for (int mf = 0; mf < 4; mf++)
#pragma unroll
        for (int nf = 0; nf < 4; nf++)
            acc[mf][nf] = (f32x4){0.f, 0.f, 0.f, 0.f};

    for (int kk = 0; kk < K; kk += 32) {
        __syncthreads();
        gld16((char*)sAh + d0, Ah + offA0 + kk);
        gld16((char*)sAh + d1, Ah + offA1 + kk);
        gld16((char*)sAl + d0, Al + offA0 + kk);
        gld16((char*)sAl + d1, Al + offA1 + kk);
        gld16((char*)sBh + d0, Bh + offB0 + kk);
        gld16((char*)sBh + d1, Bh + offB1 + kk);
        gld16((char*)sBl + d0, Bl + offB0 + kk);
        gld16((char*)sBl + d1, Bl + offB1 + kk);
        __syncthreads();

        bf16x8 fbh[4], fbl[4];
#pragma unroll
        for (int nf = 0; nf < 4; nf++) {
            int row = wn * 64 + nf * 16 + r;
            int byt = row * 64 + ((g ^ (row & 3)) * 16);
            fbh[nf] = *(const bf16x8*)((const char*)sBh + byt);
            fbl[nf] = *(const bf16x8*)((const char*)sBl + byt);
        }
#pragma unroll
        for (int mf = 0; mf < 4; mf++) {
            int row = wm * 64 + mf * 16 + r;
            int byt = row * 64 + ((g ^ (row & 3)) * 16);
            bf16x8 fah = *(const bf16x8*)((const char*)sAh + byt);
            bf16x8 fal = *(const bf16x8*)((const char*)sAl + byt);
#pragma unroll
            for (int nf = 0; nf < 4; nf++) {
                acc[mf][nf] = __builtin_amdgcn_mfma_f32_16x16x32_bf16(fal, fbh[nf], acc[mf][nf], 0, 0, 0);
                acc[mf][nf] = __builtin_amdgcn_mfma_f32_16x16x32_bf16(fah, fbl[nf], acc[mf][nf], 0, 0, 0);
                acc[mf][nf] = __builtin_amdgcn_mfma_f32_16x16x32_bf16(fah, fbh[nf], acc[mf][nf], 0, 0, 0);
            }
        }
    }

#pragma unroll
    for (int mf = 0; mf < 4; mf++)
#pragma unroll
        for (int nf = 0; nf < 4; nf++)
#pragma unroll
            for (int e = 0; e < 4; e++) {
                int row = m0 + wm * 64 + mf * 16 + 4 * g + e;
                int col = n0 + wn * 64 + nf * 16 + r;
                if (row < M) C[(size_t)row * ldc + col] = acc[mf][nf][e];
            }
}

// ---------------------------------------------------------------------------
// RMSNorm + RoPE on Q,K from fused QKV fp32 (stride 3072) -> fp16.
// ---------------------------------------------------------------------------
__global__ __launch_bounds__(256) void prep_qk(
    const float* __restrict__ QKVf, const float* __restrict__ rope,
    const float* __restrict__ qg, const float* __restrict__ kg,
    _Float16* __restrict__ Qh, _Float16* __restrict__ Kh, int L)
{
    const int l = blockIdx.x, which = blockIdx.y, t = threadIdx.x;
    const int d = t * 4;

    if (l >= L) {
        if (which == 0) { f16x4 z = {(_Float16)0, (_Float16)0, (_Float16)0, (_Float16)0};
                          *(f16x4*)(Qh + (size_t)l * 1024 + d) = z; }
        return;
    }

    const float* S = QKVf + (size_t)l * 3072 + which * 1024;
    const float* G = which ? kg : qg;
    const float qscale = which ? 1.0f : 0.18033688011112042f;
    f32x4 x = *(const f32x4*)(S + d);
    float ss = x[0] * x[0] + x[1] * x[1] + x[2] * x[2] + x[3] * x[3];
#pragma unroll
    for (int mask = 1; mask < 16; mask <<= 1)
        ss += __shfl_xor(ss, mask);
    const float inv = rsqrtf(ss * (1.0f / 64.0f) + 1e-6f);

    const int dh = d & 63;
    float xn[4];
#pragma unroll
    for (int j = 0; j < 4; j++) xn[j] = x[j] * inv * G[dh + j];
    float pn[4];
#pragma unroll
    for (int j = 0; j < 4; j++) pn[j] = __shfl_xor(xn[j], 8);

    f16x4 outv;
#pragma unroll
    for (int j = 0; j < 4; j++) {
        float ang = rope[(size_t)l * 64 + dh + j];
        float sv, cv;
        __sincosf(ang, &sv, &cv);
        float rot = (dh < 32) ? -pn[j] : pn[j];
        outv[j] = (_Float16)((xn[j] * cv + rot * sv) * qscale);
    }
    _Float16* dst = which ? Kh : Qh;
    *(f16x4*)(dst + (size_t)l * 1024 + d) = outv;
}

// ---------------------------------------------------------------------------
// V: fp32 (fused QKV, col 2048+) -> fp16 transposed [h*64+dh][L].
// ---------------------------------------------------------------------------
__global__ __launch_bounds__(256) void vtrans(
    const float* __restrict__ QKVf, _Float16* __restrict__ Vt, int L)
{
    __shared__ _Float16 T[64][72];
    const int t = threadIdx.x;
    const int l0 = blockIdx.x * 64, h = blockIdx.y;
    const int lt = t >> 2, dc = (t & 3) * 16;
    const float* src = QKVf + (size_t)(l0 + lt) * 3072 + 2048 + h * 64 + dc;
#pragma unroll
    for (int j = 0; j < 4; j++) {
        f32x4 v = *(const f32x4*)(src + 4 * j);
#pragma unroll
        for (int e = 0; e < 4; e++) T[lt][dc + 4 * j + e] = (_Float16)v[e];
    }
    __syncthreads();
    const int dh = t >> 2, seg = t & 3;
    f16x8 o0, o1;
#pragma unroll
    for (int e = 0; e < 8; e++) {
        o0[e] = T[seg * 16 + e][dh];
        o1[e] = T[seg * 16 + 8 + e][dh];
    }
    _Float16* dst = Vt + (size_t)(h * 64 + dh) * L + l0 + seg * 16;
    *(f16x8*)(dst)     = o0;
    *(f16x8*)(dst + 8) = o1;
}

// ---------------------------------------------------------------------------
// Flash attention v7 = v6 + raw v_exp_f32 + s_setprio around MFMA clusters
// + split lsum accumulators (halved fdot2 dependency chain).
// ---------------------------------------------------------------------------
__global__ __launch_bounds__(256) void flash7(
    const _Float16* __restrict__ Qh, const _Float16* __restrict__ Kh,
    const _Float16* __restrict__ Vt,
    float* __restrict__ Op, float* __restrict__ Lp, int L)
{
    __shared__ _Float16 KT[2][4096];
    __shared__ _Float16 VT[2][4096];

    const int tid = threadIdx.x, lane = tid & 63, wv = tid >> 6;
    const int r = lane & 31, g2 = lane >> 5;

    const int li  = blockIdx.x >> 3;
    const int w   = (blockIdx.x & 7) * 152 + li;
    const int h   = w / 76;
    const int rem = w % 76;
    const int s   = rem / 38;
    const int qt  = rem % 38;
    const int q0  = qt * 128 + wv * 32;
    const int t0  = s * 38;
    const int nt  = s ? 37 : 38;

    f16x8 qf[4];
#pragma unroll
    for (int kc = 0; kc < 4; kc++)
        qf[kc] = *(const f16x8*)(Qh + (size_t)(q0 + r) * 1024 + h * 64 + kc * 16 + g2 * 8);

    int loff[2][4];
#pragma unroll
    for (int blk = 0; blk < 2; blk++)
#pragma unroll
        for (int kc = 0; kc < 4; kc++)
            loff[blk][kc] = (blk * 32 + r) * 128 + (((2 * kc + g2) ^ (r & 7)) * 16);

    const int p0c = tid, p1c = 256 + tid;
    const int sr0 = p0c >> 3, sc0 = (p0c & 7) ^ (sr0 & 7);
    const int sr1 = p1c >> 3, sc1 = (p1c & 7) ^ (sr1 & 7);
    const _Float16* ksrc0 = Kh + (size_t)(t0 * 64 + sr0) * 1024 + h * 64 + sc0 * 8;
    const _Float16* ksrc1 = Kh + (size_t)(t0 * 64 + sr1) * 1024 + h * 64 + sc1 * 8;
    const _Float16* vsrc0 = Vt + (size_t)(h * 64 + sr0) * L + t0 * 64 + sc0 * 8;
    const _Float16* vsrc1 = Vt + (size_t)(h * 64 + sr1) * L + t0 * 64 + sc1 * 8;

#define STAGE(buf) do { \
        gld16((char*)&KT[buf][0] + wv * 1024,        ksrc0); \
        gld16((char*)&KT[buf][0] + 4096 + wv * 1024, ksrc1); \
        gld16((char*)&VT[buf][0] + wv * 1024,        vsrc0); \
        gld16((char*)&VT[buf][0] + 4096 + wv * 1024, vsrc1); \
        ksrc0 += 64 * 1024; ksrc1 += 64 * 1024; vsrc0 += 64; vsrc1 += 64; \
    } while (0)

    f32x16 o[2];
#pragma unroll
    for (int nb = 0; nb < 2; nb++)
#pragma unroll
        for (int e = 0; e < 16; e++) o[nb][e] = 0.f;
    float lsum0 = 0.f, lsum1 = 0.f;

    f32x16 z16;
#pragma unroll
    for (int e = 0; e < 16; e++) z16[e] = 0.f;
    const h2 ones2 = {(__fp16)1.0f, (__fp16)1.0f};

    STAGE(0);
    __syncthreads();

#define TILE(buf, dostage) do { \
        if (dostage) STAGE(buf ^ 1); \
        f32x16 sc_[2]; \
        __builtin_amdgcn_s_setprio(1); \
        _Pragma("unroll") \
        for (int mk = 0; mk < 2; mk++) { \
            f16x8 kf0 = *(const f16x8*)((const char*)&KT[buf][0] + loff[mk][0]); \
            sc_[mk] = __builtin_amdgcn_mfma_f32_32x32x16_f16(kf0, qf[0], z16, 0, 0, 0); \
            _Pragma("unroll") \
            for (int kc = 1; kc < 4; kc++) { \
                f16x8 kf = *(const f16x8*)((const char*)&KT[buf][0] + loff[mk][kc]); \
                sc_[mk] = __builtin_amdgcn_mfma_f32_32x32x16_f16(kf, qf[kc], sc_[mk], 0, 0, 0); \
            } \
        } \
        __builtin_amdgcn_s_setprio(0); \
        f16x8 pa[4]; \
        _Pragma("unroll") \
        for (int mk = 0; mk < 2; mk++) { \
            float ps[16]; \
            _Pragma("unroll") for (int e = 0; e < 16; e++) ps[e] = fexp2(sc_[mk][e]); \
            _Pragma("unroll") \
            for (int c = 0; c < 2; c++) { \
                unsigned a0 = pkrtz(ps[8 * c + 0], ps[8 * c + 1]); \
                unsigned a1 = pkrtz(ps[8 * c + 2], ps[8 * c + 3]); \
                unsigned b0 = pkrtz(ps[8 * c + 4], ps[8 * c + 5]); \
                unsigned b1 = pkrtz(ps[8 * c + 6], ps[8 * c + 7]); \
                half_exchange(a0, a1, b0, b1, g2); \
                lsum0 = __builtin_amdgcn_fdot2(__builtin_bit_cast(h2, a0), ones2, lsum0, false); \
                lsum0 = __builtin_amdgcn_fdot2(__builtin_bit_cast(h2, a1), ones2, lsum0, false); \
                lsum1 = __builtin_amdgcn_fdot2(__builtin_bit_cast(h2, b0), ones2, lsum1, false); \
                lsum1 = __builtin_amdgcn_fdot2(__builtin_bit_cast(h2, b1), ones2, lsum1, false); \
                uint4v fr = {a0, a1, b0, b1}; \
                pa[2 * mk + c] = __builtin_bit_cast(f16x8, fr); \
            } \
        } \
        __builtin_amdgcn_s_setprio(1); \
        _Pragma("unroll") \
        for (int nb = 0; nb < 2; nb++) \
            _Pragma("unroll") \
            for (int kc = 0; kc < 4; kc++) { \
                f16x8 vf = *(const f16x8*)((const char*)&VT[buf][0] + loff[nb][kc]); \
                o[nb] = __builtin_amdgcn_mfma_f32_32x32x16_f16(pa[kc], vf, o[nb], 0, 0, 0); \
            } \
        __builtin_amdgcn_s_setprio(0); \
        __syncthreads(); \
    } while (0)

    for (int t = 0; t + 2 < nt; t += 2) { TILE(0, true); TILE(1, true); }
    if (s) { TILE(0, false); }
    else   { TILE(0, true); TILE(1, false); }

#undef TILE
#undef STAGE

    float lsum = lsum0 + lsum1;
    lsum += __shfl_xor(lsum, 32);
    if (g2 == 0 && q0 + r < 4800)
        Lp[(size_t)(s * 4800 + q0 + r) * 16 + h] = lsum;
#pragma unroll
    for (int reg = 0; reg < 16; reg++) {
        const int qrow = (reg & 3) + 8 * (reg >> 2) + 4 * g2;
        const int qg = q0 + qrow;
        if (qg < 4800) {
#pragma unroll
            for (int nb = 0; nb < 2; nb++)
                Op[(size_t)(s * 4800 + qg) * 1024 + h * 64 + nb * 32 + r] = o[nb][reg];
        }
    }
}

// ---------------------------------------------------------------------------
// merge the two kv-half partials, normalize, emit bf16 hi/lo split AO.
// ---------------------------------------------------------------------------
__global__ __launch_bounds__(256) void merge_split(
    const float* __restrict__ Op, const float* __restrict__ Lp,
    short* __restrict__ AOh, short* __restrict__ AOl)
{
    const int q = blockIdx.x, t = threadIdx.x;
    const int d = t * 4, hh = d >> 6;
    f32x4 a = *(const f32x4*)(Op + (size_t)q * 1024 + d);
    f32x4 b = *(const f32x4*)(Op + (size_t)(4800 + q) * 1024 + d);
    const float inv = 1.0f / (Lp[(size_t)q * 16 + hh] + Lp[(size_t)(4800 + q) * 16 + hh]);
    short4v hv, lv;
#pragma unroll
    for (int j = 0; j < 4; j++) {
        float v = (a[j] + b[j]) * inv;
        short hbits = f2bf(v);
        hv[j] = hbits;
        lv[j] = f2bf(v - bf2f(hbits));
    }
    *(short4v*)(AOh + (size_t)q * 1024 + d) = hv;
    *(short4v*)(AOl + (size_t)q * 1024 + d) = lv;
}

// ---------------------------------------------------------------------------
extern "C" void kernel_launch(void* const* d_in, const int* in_sizes, int n_in,
                              void* d_out, int out_size, void* d_ws, size_t ws_size,
                              hipStream_t stream)
{
    const float* x    = (const float*)d_in[0];
    const float* rope = (const float*)d_in[1];
    const float* wq   = (const float*)d_in[2];
    const float* wk   = (const float*)d_in[3];
    const float* wv   = (const float*)d_in[4];
    const float* wo   = (const float*)d_in[5];
    const float* qg   = (const float*)d_in[6];
    const float* kg   = (const float*)d_in[7];
    float* out = (float*)d_out;

    const int L = 4800;
    char* ws = (char*)d_ws;

    short* Xh     = (short*)ws;
    short* Xl     = Xh + 4800 * 1024;
    short* Wqkvh  = (short*)(ws + 19660800);
    short* Wqkvl  = Wqkvh + 3 * 1024 * 1024;
    _Float16* Qh  = (_Float16*)ws;
    _Float16* Kh  = Qh + 4864 * 1024;
    _Float16* Vt  = Kh + 4800 * 1024;
    float* Lp     = (float*)(ws + 29622272);
    short* Woh    = (short*)(ws + 32243712);
    short* Wol    = Woh + 1024 * 1024;
    float* QKVf   = (float*)(ws + 36438016);
    short* AOh    = (short*)(ws + 36438016);
    short* AOl    = AOh + 4800 * 1024;
    float* Op     = (float*)(ws + 56098816);

    split_all<<<4448, 256, 0, stream>>>(x, wq, wk, wv, wo,
                                        Xh, Xl, Wqkvh, Wqkvl, Woh, Wol);

    gemm128<<<dim3(24, 38), 256, 0, stream>>>(Xh, Xl, Wqkvh, Wqkvl, QKVf, 4800, 3072, 1024, 3072);
    prep_qk<<<dim3(4864, 2), 256, 0, stream>>>(QKVf, rope, qg, kg, Qh, Kh, L);
    vtrans<<<dim3(75, 16), 256, 0, stream>>>(QKVf, Vt, L);
    flash7<<<1216, 256, 0, stream>>>(Qh, Kh, Vt, Op, Lp, L);
    merge_split<<<4800, 256, 0, stream>>>(Op, Lp, AOh, AOl);
    gemm128<<<dim3(8, 38), 256, 0, stream>>>(AOh, AOl, Woh, Wol, out, 4800, 1024, 1024, 1024);
}